// Round 11
// baseline (869.448 us; speedup 1.0000x reference)
//
#include <hip/hip_runtime.h>

// Problem constants (match reference setup_inputs)
#define NV     100000   // nodes
#define DD     128      // hidden dim
#define D2     256      // 2*D
#define EE     600000   // edges per relation
#define KK     3        // relations
#define LL     3        // layers
#define NFEAT  9
#define VOCABS 100

#define NBKT   196      // CSR buckets per relation (512 nodes each)
#define BCAP   8192     // bucket capacity (mean 3061, sigma 55 -> never hit)

typedef __attribute__((ext_vector_type(8))) short short8;
typedef __attribute__((ext_vector_type(4))) float f32x4;
typedef __attribute__((ext_vector_type(2))) float f32x2;
typedef __attribute__((ext_vector_type(4))) unsigned int uint4v;

// params layout (float offsets); BN1 affine has softmax weight a_k folded in
#define PA      0                      // a[3] = softmax(alpha[l])
#define PA2     8                      // 128: BN2 scale
#define PB2     136                    // 128: BN2 shift
#define PA1K(k) (264 + (k)*512)        // 256: a_k * BN1 scale, relation k
#define PB1K(k) (264 + (k)*512 + 256)  // 256: a_k * BN1 shift, relation k

// stats layout (float offsets): per relation zsum[256], zsq[256]; then hsum/hsq
#define ZS(k)  ((k)*512)
#define ZQ(k)  ((k)*512 + 256)
#define HSUM   1536
#define HSQ    1664

// workspace byte offsets (hb padded by 8 zero rows -> zero-row gather trick)
#define HB_OFF   ((size_t)0)            // h (bf16)     (N+8)*128
#define ZIN_OFF  ((size_t)25700000)     // zin_k (bf16) 3 x N*128 ; CSR pairs aliased
#define HNB_OFF  ((size_t)102500000)    // h_next (bf16) N*128
#define O_BASE   ((size_t)128100000)

__device__ __forceinline__ unsigned short f2bf(float f) {
    union { float f; unsigned int u; } v; v.f = f;
    return (unsigned short)((v.u + 0x7FFFu + ((v.u >> 16) & 1u)) >> 16);
}
__device__ __forceinline__ float bf2f(unsigned short u) {
    union { unsigned int u; float f; } v; v.u = ((unsigned int)u) << 16;
    return v.f;
}
// unpack a bf16 pair (one u32) to f32x2 {lo, hi}
__device__ __forceinline__ f32x2 up2(unsigned int v) {
    union { unsigned int u[2]; f32x2 f; } w;
    w.u[0] = v << 16;
    w.u[1] = v & 0xFFFF0000u;
    return w.f;
}

// h[n,d] = sum_f emb[f, x[n,f], d] -> bf16 ; rows NV..NV+7 zeroed (gather dummy)
__global__ void k_embed(const int* __restrict__ x, const float* __restrict__ emb,
                        unsigned short* __restrict__ hb) {
    int id = blockIdx.x*256 + threadIdx.x;
    int n = id >> 5, q = id & 31;
    if (n >= NV) {
        if (n < NV + 8) *(unsigned long long*)(hb + (size_t)n*DD + q*4) = 0ull;
        return;
    }
    const int* xr = x + n*NFEAT;
    f32x4 acc = {0.f,0.f,0.f,0.f};
    #pragma unroll
    for (int f = 0; f < NFEAT; ++f) {
        int idx = xr[f];
        acc += *(const f32x4*)(emb + ((size_t)(f*VOCABS + idx)*DD + q*4));
    }
    unsigned short pk[4];
    pk[0] = f2bf(acc[0]); pk[1] = f2bf(acc[1]); pk[2] = f2bf(acc[2]); pk[3] = f2bf(acc[3]);
    *(unsigned long long*)(hb + (size_t)n*DD + q*4) = *(unsigned long long*)pk;
}

// ---- CSR build: radix-binned, write-amplification-free ----
__global__ void kA_bin(const int* __restrict__ ke, int* __restrict__ cursor,
                       uint2* __restrict__ pairs) {
    __shared__ int hist[NBKT], excl[NBKT], ofs[NBKT], gbase[NBKT];
    __shared__ int sc[256];
    __shared__ uint2 buf[4096];
    const int rel = blockIdx.y, t = threadIdx.x;
    const int e0 = blockIdx.x * 4096;
    const int cnt = min(4096, EE - e0);
    const int* srcA = ke + (size_t)(rel*2)*EE + e0;
    const int* dstA = ke + (size_t)(rel*2+1)*EE + e0;
    if (t < NBKT) hist[t] = 0;
    __syncthreads();
    for (int i = t; i < cnt; i += 256) atomicAdd(&hist[dstA[i] >> 9], 1);
    __syncthreads();
    const int hv = (t < NBKT) ? hist[t] : 0;
    sc[t] = hv;
    for (int off = 1; off < 256; off <<= 1) {
        __syncthreads();
        int v = (t >= off) ? sc[t-off] : 0;
        __syncthreads();
        sc[t] += v;
    }
    __syncthreads();
    if (t < NBKT) {
        excl[t] = sc[t] - hv;
        ofs[t]  = sc[t] - hv;
        if (hv > 0) gbase[t] = atomicAdd(&cursor[rel*NBKT + t], hv);
    }
    __syncthreads();
    for (int i = t; i < cnt; i += 256) {
        unsigned int s = (unsigned int)srcA[i], d = (unsigned int)dstA[i];
        int p = atomicAdd(&ofs[d >> 9], 1);
        uint2 u; u.x = s; u.y = d;
        buf[p] = u;
    }
    __syncthreads();
    for (int i = t; i < cnt; i += 256) {
        uint2 u = buf[i];
        int b = (int)(u.y >> 9);
        int pos = gbase[b] + (i - excl[b]);
        if (pos < BCAP) pairs[(size_t)(rel*NBKT + b)*BCAP + pos] = u;
    }
}

__global__ void kB_scan(const int* __restrict__ cursor, int* __restrict__ ebase) {
    __shared__ int sc[256];
    const int t = threadIdx.x;
    for (int rel = 0; rel < KK; ++rel) {
        int hv = (t < NBKT) ? min(cursor[rel*NBKT + t], BCAP) : 0;
        sc[t] = hv;
        for (int off = 1; off < 256; off <<= 1) {
            __syncthreads();
            int v = (t >= off) ? sc[t-off] : 0;
            __syncthreads();
            sc[t] += v;
        }
        __syncthreads();
        if (t < NBKT) ebase[rel*NBKT + t] = sc[t] - hv;
        __syncthreads();
    }
}

__global__ void kB_fill(const uint2* __restrict__ pairs, const int* __restrict__ cursor,
                        const int* __restrict__ ebase, int* __restrict__ rp,
                        int* __restrict__ col) {
    __shared__ int h2[512], excl[512], cur[512], sc[256];
    const int b = blockIdx.x, rel = blockIdx.y, t = threadIdx.x;
    const int lo = b * 512;
    const int cnt = min(cursor[rel*NBKT + b], BCAP);
    const int base = ebase[rel*NBKT + b];
    const uint2* P = pairs + (size_t)(rel*NBKT + b)*BCAP;
    h2[t] = 0; h2[t+256] = 0; cur[t] = 0; cur[t+256] = 0;
    __syncthreads();
    for (int i = t; i < cnt; i += 256) atomicAdd(&h2[(int)P[i].y - lo], 1);
    __syncthreads();
    const int a0 = h2[2*t], a1 = h2[2*t+1];
    sc[t] = a0 + a1;
    for (int off = 1; off < 256; off <<= 1) {
        __syncthreads();
        int v = (t >= off) ? sc[t-off] : 0;
        __syncthreads();
        sc[t] += v;
    }
    __syncthreads();
    const int e2 = sc[t] - (a0 + a1);
    excl[2*t] = e2; excl[2*t+1] = e2 + a0;
    __syncthreads();
    for (int tt = t; tt < 512; tt += 256) {
        int n = lo + tt;
        if (n <= NV) rp[(size_t)rel*(NV+1) + n] = base + excl[tt];
    }
    for (int i = t; i < cnt; i += 256) {
        uint2 u = P[i];
        int r = (int)u.y - lo;
        int p = atomicAdd(&cur[r], 1);
        col[(size_t)rel*EE + base + excl[r] + p] = (int)u.x;
    }
}

// Per layer: pack W1/W2 to bf16 MFMA fragments; compute softmax(alpha[l])
__global__ void k_prep(const float* __restrict__ W1, const float* __restrict__ W2,
                       const float* __restrict__ alpha, const int l,
                       unsigned short* __restrict__ w1f, unsigned short* __restrict__ w2f,
                       float* __restrict__ params) {
    int id = blockIdx.x*256 + threadIdx.x;
    if (id == 0) {
        float a0 = alpha[l*KK+0], a1 = alpha[l*KK+1], a2 = alpha[l*KK+2];
        float m = fmaxf(a0, fmaxf(a1, a2));
        float e0 = expf(a0-m), e1 = expf(a1-m), e2 = expf(a2-m);
        float inv = 1.f/(e0+e1+e2);
        params[PA+0] = e0*inv; params[PA+1] = e1*inv; params[PA+2] = e2*inv;
    }
    if (id < 4096) {                       // W1: [128][256]
        int kt = id >> 10, nt = (id >> 6) & 15, lane = id & 63;
        int r = lane & 15, g = lane >> 4;
        const float* Wl = W1 + (size_t)l*DD*D2;
        #pragma unroll
        for (int e = 0; e < 8; ++e) {
            int kk = kt*32 + g*8 + e, c = nt*16 + r;
            w1f[(size_t)id*8 + e] = f2bf(Wl[(size_t)kk*D2 + c]);
        }
    } else if (id < 8192) {                // W2: [256][128]
        int id2 = id - 4096;
        int kt = id2 >> 9, nt = (id2 >> 6) & 7, lane = id2 & 63;
        int r = lane & 15, g = lane >> 4;
        const float* Wl = W2 + (size_t)l*D2*DD;
        #pragma unroll
        for (int e = 0; e < 8; ++e) {
            int kk = kt*32 + g*8 + e, c = nt*16 + r;
            w2f[(size_t)id2*8 + e] = f2bf(Wl[(size_t)kk*DD + c]);
        }
    }
}

// zin_k[n,:] = bf16( (1+eps)*h[n,:] + sum_{j->n,k} h[j,:] )  for all 3 relations.
// One wave per node (n wave-uniform -> SGPR). Neighbor indices preloaded
// coalesced; __shfl broadcast on uniform control flow; invalid lanes point at
// the ZERO row (NV) so the edge loop has no predicates/exec-mask churn.
__global__ void k_gather3(const unsigned short* __restrict__ hb, const int* __restrict__ rp,
                          const int* __restrict__ col, const float* __restrict__ epsp,
                          unsigned short* __restrict__ zin) {
    int gid = blockIdx.x*256 + threadIdx.x;
    int n0 = gid >> 6;
    if (n0 >= NV) return;
    const int n = __builtin_amdgcn_readfirstlane(n0);   // wave-uniform -> SGPR
    const int lane = threadIdx.x & 63;
    const int q = lane >> 4, r = lane & 15;
    const int r16 = r << 4;
    const char* hbase = (const char*)hb;
    const float epsv = 1.0f + epsp[0];
    const uint4v sv = *(const uint4v*)(hbase + (((unsigned)n << 8) + r16));
    int b0[KK], dg[KK], cv[KK];
    #pragma unroll
    for (int k = 0; k < KK; ++k) {
        int a = rp[k*(NV+1) + n];
        int b = rp[k*(NV+1) + n + 1];
        b0[k] = a; dg[k] = b - a;
        cv[k] = (lane < dg[k]) ? col[(size_t)k*EE + a + lane] : NV;  // NV = zero row
    }
    f32x2 acc[KK][4];
    #pragma unroll
    for (int k = 0; k < KK; ++k)
        #pragma unroll
        for (int c = 0; c < 4; ++c) acc[k][c] = (f32x2){0.f, 0.f};
    #pragma unroll
    for (int k = 0; k < KK; ++k) {
        const int dc = min(dg[k], 64);            // wave-uniform bound
        for (int base = 0; base < dc; base += 8) {
            int s0 = __shfl(cv[k], base + q);      // lanes all active; idx <= 63
            int s1 = __shfl(cv[k], base + q + 4);
            uint4v v0 = *(const uint4v*)(hbase + (((unsigned)s0 << 8) + r16));
            uint4v v1 = *(const uint4v*)(hbase + (((unsigned)s1 << 8) + r16));
            #pragma unroll
            for (int c = 0; c < 4; ++c) {
                acc[k][c] += up2(v0[c]);
                acc[k][c] += up2(v1[c]);
            }
        }
        // deg > 64 tail: direct col loads (no cross-lane ops)
        for (int j = b0[k] + 64 + q; j < b0[k] + dg[k]; j += 4) {
            int s0 = col[(size_t)k*EE + j];
            uint4v v0 = *(const uint4v*)(hbase + (((unsigned)s0 << 8) + r16));
            #pragma unroll
            for (int c = 0; c < 4; ++c) acc[k][c] += up2(v0[c]);
        }
    }
    #pragma unroll
    for (int k = 0; k < KK; ++k) {
        #pragma unroll
        for (int c = 0; c < 4; ++c) {
            acc[k][c][0] += __shfl_xor(acc[k][c][0], 16);
            acc[k][c][1] += __shfl_xor(acc[k][c][1], 16);
            acc[k][c][0] += __shfl_xor(acc[k][c][0], 32);
            acc[k][c][1] += __shfl_xor(acc[k][c][1], 32);
        }
    }
    if (q == 0) {
        #pragma unroll
        for (int k = 0; k < KK; ++k) {
            uint4v pk;
            #pragma unroll
            for (int c = 0; c < 4; ++c) {
                f32x2 s2 = up2(sv[c]);
                float lo = acc[k][c][0] + epsv * s2[0];
                float hi = acc[k][c][1] + epsv * s2[1];
                unsigned int pko;
                asm("v_cvt_pk_bf16_f32 %0, %1, %2" : "=v"(pko) : "v"(lo), "v"(hi));
                pk[c] = pko;
            }
            *(uint4v*)((char*)zin + (size_t)k*NV*DD*2 + (((unsigned)n << 8) + r16)) = pk;
        }
    }
}

// BN1 stats of z1_k = zin_k @ W1 for all relations (grid.y = k), z1 never stored.
__launch_bounds__(256, 2)
__global__ void k_stats3(const unsigned short* __restrict__ zin,
                         const unsigned short* __restrict__ w1f,
                         float* __restrict__ stats) {
    __shared__ __align__(16) unsigned short bfr1[32768];  // 64KB W1 frags
    __shared__ float scf[1024];
    const int t = threadIdx.x;
    const int krel = blockIdx.y;
    const unsigned short* zk = zin + (size_t)krel*NV*DD;
    float* zsum = stats + ZS(krel);
    float* zsq  = stats + ZQ(krel);
    for (int i = t; i < 4096; i += 256)
        *(uint4v*)(bfr1 + i*8) = *(const uint4v*)(w1f + i*8);
    const int lane = t & 63, w = t >> 6;
    const int r_ = lane & 15, g = lane >> 4;
    const int rt = w & 1, ch = w >> 1;
    __syncthreads();
    float ssum[8] = {0,0,0,0,0,0,0,0};
    float ssq[8]  = {0,0,0,0,0,0,0,0};
    for (int tile = blockIdx.x; tile < NV/32; tile += gridDim.x) {
        const int row0 = tile*32;
        short8 af[4];
        #pragma unroll
        for (int kt = 0; kt < 4; ++kt)
            af[kt] = *(const short8*)(zk + (size_t)(row0 + rt*16 + r_)*DD + kt*32 + g*8);
        #pragma unroll
        for (int ct = 0; ct < 8; ++ct) {
            const int ntg = ch*8 + ct;
            f32x4 c = {0.f,0.f,0.f,0.f};
            #pragma unroll
            for (int kt = 0; kt < 4; ++kt) {
                short8 b = *(const short8*)(bfr1 + ((size_t)((kt*16 + ntg)*64 + lane))*8);
                c = __builtin_amdgcn_mfma_f32_16x16x32_bf16(af[kt], b, c, 0, 0, 0);
            }
            float s = c[0]+c[1]+c[2]+c[3];
            float q = c[0]*c[0]+c[1]*c[1]+c[2]*c[2]+c[3]*c[3];
            s += __shfl_xor(s, 16); q += __shfl_xor(q, 16);
            s += __shfl_xor(s, 32); q += __shfl_xor(q, 32);
            ssum[ct] += s; ssq[ct] += q;
        }
    }
    if (g == 0) {
        #pragma unroll
        for (int ct = 0; ct < 8; ++ct) {
            const int colc = (ch*8 + ct)*16 + r_;
            scf[rt*256 + colc]       = ssum[ct];
            scf[512 + rt*256 + colc] = ssq[ct];
        }
    }
    __syncthreads();
    atomicAdd(zsum + t, scf[t]       + scf[256 + t]);
    atomicAdd(zsq  + t, scf[512 + t] + scf[768 + t]);
}

// BN1 affine for all 3 relations, a_k folded in (a_k>0: a*relu(u) = relu(a*u))
__global__ void k_bnprep3(float* __restrict__ stats,
                          const float* __restrict__ g1l, const float* __restrict__ be1l,
                          float* __restrict__ params) {
    int j = threadIdx.x;  // 256
    #pragma unroll
    for (int k = 0; k < KK; ++k) {
        float ak  = params[PA + k];
        float mu  = stats[ZS(k) + j] * (1.0f/NV);
        float var = stats[ZQ(k) + j] * (1.0f/NV) - mu*mu;
        float A = g1l[j] * rsqrtf(var + 1e-5f);
        params[PA1K(k) + j] = ak * A;
        params[PB1K(k) + j] = ak * (be1l[j] - mu*A);
        stats[ZS(k) + j] = 0.0f; stats[ZQ(k) + j] = 0.0f;   // re-zero for next layer
    }
}

// hn = [ sum_k relu(A''_k (zin_k @ W1) + B''_k) ] @ W2 + hn column stats.
// 16 waves. zin tile (24KB) reg-staged coalesced -> swizzled LDS (double
// buffered, loads issued one tile ahead) -- kills the 16-segment-per-load
// fragmentation of direct af loads. W1 in LDS; W2 frags in registers (each
// wave needs only its own output column: 8 x short8). One barrier per tile.
// LDS = 64 (W1) + 2x24 (zin stage) + 2x16 (y tile) = 144 KiB.

#define GLOAD(SA, SB, TT) {                                                        \
    const char* p_ = (const char*)zin + (size_t)(TT)*8192;                         \
    SA = *(const uint4v*)(p_ + gsrcA);                                             \
    if (t < 512) SB = *(const uint4v*)(p_ + gsrcB);                                \
}

#define GITER(ZSRD, YTBUF, ZSWR, SWA, SWB, SLA, SLB) {                             \
    const int cur_ = tile;                                                         \
    /* phase 1: y = sum_k relu(BN1_k(zin_k @ W1)); af from staged LDS */           \
    f32x4 y[2];                                                                    \
    y[0] = (f32x4){0.f,0.f,0.f,0.f};                                               \
    y[1] = (f32x4){0.f,0.f,0.f,0.f};                                               \
    _Pragma("unroll")                                                              \
    for (int k = 0; k < KK; ++k) {                                                 \
        short8 af[4];                                                              \
        _Pragma("unroll")                                                          \
        for (int kt = 0; kt < 4; ++kt)                                             \
            af[kt] = *(const short8*)(ZSRD + k*8192 + (rt*16 + r_)*256             \
                         + ((((kt*4 + g) ^ r_) & 15) << 4));                       \
        _Pragma("unroll")                                                          \
        for (int ct = 0; ct < 2; ++ct) {                                           \
            f32x4 c = {0.f,0.f,0.f,0.f};                                           \
            _Pragma("unroll")                                                      \
            for (int kt = 0; kt < 4; ++kt) {                                       \
                short8 b = *(const short8*)(bfr1 + ((size_t)((kt*16 + ch*2 + ct)*64 + lane))*8); \
                c = __builtin_amdgcn_mfma_f32_16x16x32_bf16(af[kt], b, c, 0, 0, 0); \
            }                                                                      \
            _Pragma("unroll")                                                      \
            for (int reg = 0; reg < 4; ++reg)                                      \
                y[ct][reg] += fmaxf(pa1[k][ct]*c[reg] + pb1[k][ct], 0.0f);         \
        }                                                                          \
    }                                                                              \
    /* y -> yt (swizzled bf16) */                                                  \
    _Pragma("unroll")                                                              \
    for (int ct = 0; ct < 2; ++ct) {                                               \
        const int col2 = ((ch*2 + ct)*16 + r_)*2;                                  \
        _Pragma("unroll")                                                          \
        for (int reg = 0; reg < 4; ++reg) {                                        \
            const int row = rt*16 + g*4 + reg;                                     \
            *(unsigned short*)(YTBUF + row*512 + (col2 ^ ((row & 15) << 4))) = f2bf(y[ct][reg]); \
        }                                                                          \
    }                                                                              \
    /* stage next tile's zin (regs loaded one tile ago) into LDS */                \
    if (cur_ + step < NT) {                                                        \
        *(uint4v*)(ZSWR + dstA) = SWA;                                             \
        if (t < 512) *(uint4v*)(ZSWR + dstB) = SWB;                                \
    }                                                                              \
    __syncthreads();                                                               \
    /* issue coalesced global loads for tile+2*step */                             \
    if (cur_ + 2*step < NT) GLOAD(SLA, SLB, cur_ + 2*step);                        \
    /* phase 2: hn = y @ W2 (W2 in regs) */                                        \
    short8 ya[8];                                                                  \
    _Pragma("unroll")                                                              \
    for (int kt = 0; kt < 8; ++kt)                                                 \
        ya[kt] = *(const short8*)(YTBUF + arow*512 + ((kt*64 + g*16) ^ ((arow & 15) << 4))); \
    f32x4 c2 = {0.f,0.f,0.f,0.f};                                                  \
    _Pragma("unroll")                                                              \
    for (int kt = 0; kt < 8; ++kt)                                                 \
        c2 = __builtin_amdgcn_mfma_f32_16x16x32_bf16(ya[kt], wb[kt], c2, 0, 0, 0); \
    unsigned short* hp = hnb + (size_t)(cur_*32 + rt*16 + g*4)*DD + ch*16 + r_;    \
    float ps = 0.0f, pq = 0.0f;                                                    \
    _Pragma("unroll")                                                              \
    for (int reg = 0; reg < 4; ++reg) {                                            \
        float xv = c2[reg];                                                        \
        hp[(size_t)reg*DD] = f2bf(xv);                                             \
        ps += xv; pq += xv*xv;                                                     \
    }                                                                              \
    ps += __shfl_xor(ps, 16); pq += __shfl_xor(pq, 16);                            \
    ps += __shfl_xor(ps, 32); pq += __shfl_xor(pq, 32);                            \
    ssum0 += ps; ssq0 += pq;                                                       \
    tile += step;                                                                  \
}

__launch_bounds__(1024, 1)
__global__ void k_gemm2f(const unsigned short* __restrict__ zin,
                         const unsigned short* __restrict__ w1f,
                         const unsigned short* __restrict__ w2f,
                         const float* __restrict__ params,
                         unsigned short* __restrict__ hnb,
                         float* __restrict__ hsum, float* __restrict__ hsq) {
    __shared__ __align__(16) unsigned short bfr1[32768];   // 64KB W1 frags
    __shared__ __align__(16) unsigned char zs0[24576];     // staged zin (3 rel x 32 x 256B)
    __shared__ __align__(16) unsigned char zs1[24576];
    __shared__ __align__(16) unsigned char yt0[16384];     // 32 x 256 bf16, swizzled
    __shared__ __align__(16) unsigned char yt1[16384];
    const int t = threadIdx.x;
    for (int i = t; i < 4096; i += 1024)
        *(uint4v*)(bfr1 + i*8) = *(const uint4v*)(w1f + i*8);
    const int lane = t & 63, w = t >> 6;          // 16 waves
    const int r_ = lane & 15, g = lane >> 4;
    const int rt = w & 1, ch = w >> 1;            // rt: row half, ch: col eighth
    const int arow = rt*16 + r_;
    // W2 B-frags for this wave's output column -> registers (replaces 64KB LDS)
    short8 wb[8];
    #pragma unroll
    for (int kt = 0; kt < 8; ++kt)
        wb[kt] = *(const short8*)(w2f + ((size_t)((kt*8 + ch)*64 + lane))*8);
    float pa1[KK][2], pb1[KK][2];
    #pragma unroll
    for (int k = 0; k < KK; ++k) {
        #pragma unroll
        for (int ct = 0; ct < 2; ++ct) {
            const int colc = (ch*2 + ct)*16 + r_;
            pa1[k][ct] = params[PA1K(k) + colc];
            pb1[k][ct] = params[PB1K(k) + colc];
        }
    }
    // staging geometry: granule = 16B; thread t handles granule t and (t<512)
    // granule 1024+t. granule -> (k = g/512, row = (g%512)/16, c16 = g%16).
    // LDS slot swizzle c16 ^= row&15: bank-balanced for BOTH ds_write_b128
    // (staging) and ds_read_b128 (af frags) -- 8 lanes/bank-quad each.
    const int kA = t >> 9, remA = t & 511, rowA = remA >> 4, cA = remA & 15;
    const size_t gsrcA = (size_t)kA*((size_t)NV*256) + (size_t)rowA*256 + (size_t)cA*16;
    const int dstA = kA*8192 + rowA*256 + (((cA ^ rowA) & 15) << 4);
    const int rowB = (t & 511) >> 4, cB = t & 15;
    const size_t gsrcB = (size_t)2*((size_t)NV*256) + (size_t)rowB*256 + (size_t)cB*16;
    const int dstB = 2*8192 + rowB*256 + (((cB ^ rowB) & 15) << 4);

    const int NT = NV/32;
    const int step = gridDim.x;
    int tile = blockIdx.x;
    uint4v s0A = {0,0,0,0}, s0B = {0,0,0,0}, s1A = {0,0,0,0}, s1B = {0,0,0,0};
    GLOAD(s0A, s0B, tile);
    *(uint4v*)(zs0 + dstA) = s0A;
    if (t < 512) *(uint4v*)(zs0 + dstB) = s0B;
    if (tile + step < NT) GLOAD(s1A, s1B, tile + step);
    __syncthreads();   // zs0 + bfr1 visible
    float ssum0 = 0.0f, ssq0 = 0.0f;
    while (tile < NT) {
        GITER(zs0, yt0, zs1, s1A, s1B, s0A, s0B);
        if (tile >= NT) break;
        GITER(zs1, yt1, zs0, s0A, s0B, s1A, s1B);
    }
    // flush hn column stats (reuse yt0 as scratch)
    __syncthreads();
    float* scf = (float*)yt0;
    if (g == 0) {
        scf[rt*128 + ch*16 + r_]       = ssum0;
        scf[256 + rt*128 + ch*16 + r_] = ssq0;
    }
    __syncthreads();
    if (t < 128) {
        atomicAdd(hsum + t, scf[t]       + scf[128 + t]);
        atomicAdd(hsq  + t, scf[256 + t] + scf[384 + t]);
    }
}

__global__ void k_bnprep2(float* __restrict__ hsum, float* __restrict__ hsq,
                          const float* __restrict__ bng, const float* __restrict__ bnb,
                          float* __restrict__ params) {
    int j = threadIdx.x;  // 128
    float mu  = hsum[j] * (1.0f/NV);
    float var = hsq[j]  * (1.0f/NV) - mu*mu;
    float A = bng[j] * rsqrtf(var + 1e-5f);
    params[PA2 + j] = A;
    params[PB2 + j] = bnb[j] - mu*A;
    hsum[j] = 0.0f; hsq[j] = 0.0f;
}

// mid layers: h(bf16) = relu(BN2(hn))
__global__ void k_bnapply_mid(const unsigned short* __restrict__ hnb,
                              const float* __restrict__ params,
                              unsigned short* __restrict__ hb) {
    int id = blockIdx.x*256 + threadIdx.x;       // 6250 blocks * 8 elems
    const int col0 = (id & 15)*8;
    short8 v = *(const short8*)(hnb + (size_t)id*8);
    f32x4 A0 = *(const f32x4*)(params + PA2 + col0);
    f32x4 A1 = *(const f32x4*)(params + PA2 + col0 + 4);
    f32x4 B0 = *(const f32x4*)(params + PB2 + col0);
    f32x4 B1 = *(const f32x4*)(params + PB2 + col0 + 4);
    short8 o;
    #pragma unroll
    for (int j = 0; j < 4; ++j) {
        o[j]   = (short)f2bf(fmaxf(A0[j]*bf2f((unsigned short)v[j])   + B0[j], 0.0f));
        o[j+4] = (short)f2bf(fmaxf(A1[j]*bf2f((unsigned short)v[j+4]) + B1[j], 0.0f));
    }
    *(short8*)(hb + (size_t)id*8) = o;
}

// final layer: d_out(f32) = relu(BN2(hn))
__global__ void k_bnapply_fin(const unsigned short* __restrict__ hnb,
                              const float* __restrict__ params,
                              float* __restrict__ out) {
    int id = blockIdx.x*256 + threadIdx.x;
    const int col0 = (id & 15)*8;
    short8 v = *(const short8*)(hnb + (size_t)id*8);
    f32x4 A0 = *(const f32x4*)(params + PA2 + col0);
    f32x4 A1 = *(const f32x4*)(params + PA2 + col0 + 4);
    f32x4 B0 = *(const f32x4*)(params + PB2 + col0);
    f32x4 B1 = *(const f32x4*)(params + PB2 + col0 + 4);
    f32x4 o0, o1;
    #pragma unroll
    for (int j = 0; j < 4; ++j) {
        o0[j] = fmaxf(A0[j]*bf2f((unsigned short)v[j])   + B0[j], 0.0f);
        o1[j] = fmaxf(A1[j]*bf2f((unsigned short)v[j+4]) + B1[j], 0.0f);
    }
    *(f32x4*)(out + (size_t)id*8)     = o0;
    *(f32x4*)(out + (size_t)id*8 + 4) = o1;
}

extern "C" void kernel_launch(void* const* d_in, const int* in_sizes, int n_in,
                              void* d_out, int out_size, void* d_ws, size_t ws_size,
                              hipStream_t stream) {
    const int*   x     = (const int*)d_in[0];
    const int*   ke    = (const int*)d_in[1];
    const float* emb   = (const float*)d_in[2];
    const float* W1    = (const float*)d_in[3];
    // d_in[4] = b1: per-column shift cancels exactly through training-mode BN
    const float* g1    = (const float*)d_in[5];
    const float* be1   = (const float*)d_in[6];
    const float* W2    = (const float*)d_in[7];
    // d_in[8] = b2: cancels through final BN (softmax weights sum to 1)
    const float* eps   = (const float*)d_in[9];
    const float* alpha = (const float*)d_in[10];
    const float* bng   = (const float*)d_in[11];
    const float* bnb   = (const float*)d_in[12];

    char* ws = (char*)d_ws;
    unsigned short* hb     = (unsigned short*)(ws + HB_OFF);
    unsigned short* zin    = (unsigned short*)(ws + ZIN_OFF);   // 3 buffers
    unsigned short* hnb    = (unsigned short*)(ws + HNB_OFF);
    size_t o = O_BASE;
    unsigned short* w1f    = (unsigned short*)(ws + o);          o += 65536;
    unsigned short* w2f    = (unsigned short*)(ws + o);          o += 65536;
    float*          stats  = (float*)(ws + o);                   o += 8192;
    float*          params = (float*)(ws + o);                   o += 8192;
    int*            rp     = (int*)(ws + o);                     o += 1200128;
    int*            col    = (int*)(ws + o);                     o += 7200000;
    int*            cur    = (int*)(ws + o);                     o += 4096;
    int*            ebase  = (int*)(ws + o);                     o += 4096;
    uint2*          pairs  = (uint2*)(ws + ZIN_OFF);             // aliased (pre-zin)

    // AtomEncoder (+ zero-pad rows NV..NV+7 for the gather dummy row)
    k_embed<<<12501, 256, 0, stream>>>(x, emb, hb);

    // CSR build (shared by all layers; uses pairs alias before any zin write)
    hipMemsetAsync(cur, 0, KK*NBKT*sizeof(int), stream);
    hipMemsetAsync(stats, 0, 8192, stream);
    kA_bin<<<dim3(147, KK), 256, 0, stream>>>(ke, cur, pairs);
    kB_scan<<<1, 256, 0, stream>>>(cur, ebase);
    kB_fill<<<dim3(NBKT, KK), 256, 0, stream>>>(pairs, cur, ebase, rp, col);

    for (int l = 0; l < LL; ++l) {
        k_prep<<<32, 256, 0, stream>>>(W1, W2, alpha, l, w1f, w2f, params);
        k_gather3<<<25000, 256, 0, stream>>>(hb, rp, col, eps + l, zin);
        k_stats3<<<dim3(512, KK), 256, 0, stream>>>(zin, w1f, stats);
        k_bnprep3<<<1, 256, 0, stream>>>(stats, g1 + l*D2, be1 + l*D2, params);
        k_gemm2f<<<256, 1024, 0, stream>>>(zin, w1f, w2f, params, hnb,
                                           stats + HSUM, stats + HSQ);
        k_bnprep2<<<1, 128, 0, stream>>>(stats + HSUM, stats + HSQ,
                                         bng + l*DD, bnb + l*DD, params);
        if (l < LL-1) k_bnapply_mid<<<6250, 256, 0, stream>>>(hnb, params, hb);
        else          k_bnapply_fin<<<6250, 256, 0, stream>>>(hnb, params, (float*)d_out);
    }
}

// Round 12
// 750.123 us; speedup vs baseline: 1.1591x; 1.1591x over previous
//
#include <hip/hip_runtime.h>

// Problem constants (match reference setup_inputs)
#define NV     100000   // nodes
#define DD     128      // hidden dim
#define D2     256      // 2*D
#define EE     600000   // edges per relation
#define KK     3        // relations
#define LL     3        // layers
#define NFEAT  9
#define VOCABS 100

#define NBKT   196      // CSR buckets per relation (512 nodes each)
#define BCAP   8192     // bucket capacity (mean 3061, sigma 55 -> never hit)

typedef __attribute__((ext_vector_type(8))) short short8;
typedef __attribute__((ext_vector_type(4))) float f32x4;
typedef __attribute__((ext_vector_type(2))) float f32x2;
typedef __attribute__((ext_vector_type(4))) unsigned int uint4v;

// params layout (float offsets); BN1 affine has softmax weight a_k folded in
#define PA      0                      // a[3] = softmax(alpha[l])
#define PA2     8                      // 128: BN2 scale
#define PB2     136                    // 128: BN2 shift
#define PA1K(k) (264 + (k)*512)        // 256: a_k * BN1 scale, relation k
#define PB1K(k) (264 + (k)*512 + 256)  // 256: a_k * BN1 shift, relation k

// stats layout (float offsets): per relation zsum[256], zsq[256]; then hsum/hsq
#define ZS(k)  ((k)*512)
#define ZQ(k)  ((k)*512 + 256)
#define HSUM   1536
#define HSQ    1664

// workspace byte offsets (hb padded by 8 zero rows -> zero-row gather trick)
#define HB_OFF   ((size_t)0)            // h (bf16)     (N+8)*128
#define ZIN_OFF  ((size_t)25700000)     // zin_k (bf16) 3 x N*128 ; CSR pairs aliased
#define HNB_OFF  ((size_t)102500000)    // h_next (bf16) N*128
#define O_BASE   ((size_t)128100000)

__device__ __forceinline__ unsigned short f2bf(float f) {
    union { float f; unsigned int u; } v; v.f = f;
    return (unsigned short)((v.u + 0x7FFFu + ((v.u >> 16) & 1u)) >> 16);
}
__device__ __forceinline__ float bf2f(unsigned short u) {
    union { unsigned int u; float f; } v; v.u = ((unsigned int)u) << 16;
    return v.f;
}
// unpack a bf16 pair (one u32) to f32x2 {lo, hi}
__device__ __forceinline__ f32x2 up2(unsigned int v) {
    union { unsigned int u[2]; f32x2 f; } w;
    w.u[0] = v << 16;
    w.u[1] = v & 0xFFFF0000u;
    return w.f;
}

// h[n,d] = sum_f emb[f, x[n,f], d] -> bf16 ; rows NV..NV+7 zeroed (gather dummy)
__global__ void k_embed(const int* __restrict__ x, const float* __restrict__ emb,
                        unsigned short* __restrict__ hb) {
    int id = blockIdx.x*256 + threadIdx.x;
    int n = id >> 5, q = id & 31;
    if (n >= NV) {
        if (n < NV + 8) *(unsigned long long*)(hb + (size_t)n*DD + q*4) = 0ull;
        return;
    }
    const int* xr = x + n*NFEAT;
    f32x4 acc = {0.f,0.f,0.f,0.f};
    #pragma unroll
    for (int f = 0; f < NFEAT; ++f) {
        int idx = xr[f];
        acc += *(const f32x4*)(emb + ((size_t)(f*VOCABS + idx)*DD + q*4));
    }
    unsigned short pk[4];
    pk[0] = f2bf(acc[0]); pk[1] = f2bf(acc[1]); pk[2] = f2bf(acc[2]); pk[3] = f2bf(acc[3]);
    *(unsigned long long*)(hb + (size_t)n*DD + q*4) = *(unsigned long long*)pk;
}

// ---- CSR build: radix-binned, write-amplification-free ----
__global__ void kA_bin(const int* __restrict__ ke, int* __restrict__ cursor,
                       uint2* __restrict__ pairs) {
    __shared__ int hist[NBKT], excl[NBKT], ofs[NBKT], gbase[NBKT];
    __shared__ int sc[256];
    __shared__ uint2 buf[4096];
    const int rel = blockIdx.y, t = threadIdx.x;
    const int e0 = blockIdx.x * 4096;
    const int cnt = min(4096, EE - e0);
    const int* srcA = ke + (size_t)(rel*2)*EE + e0;
    const int* dstA = ke + (size_t)(rel*2+1)*EE + e0;
    if (t < NBKT) hist[t] = 0;
    __syncthreads();
    for (int i = t; i < cnt; i += 256) atomicAdd(&hist[dstA[i] >> 9], 1);
    __syncthreads();
    const int hv = (t < NBKT) ? hist[t] : 0;
    sc[t] = hv;
    for (int off = 1; off < 256; off <<= 1) {
        __syncthreads();
        int v = (t >= off) ? sc[t-off] : 0;
        __syncthreads();
        sc[t] += v;
    }
    __syncthreads();
    if (t < NBKT) {
        excl[t] = sc[t] - hv;
        ofs[t]  = sc[t] - hv;
        if (hv > 0) gbase[t] = atomicAdd(&cursor[rel*NBKT + t], hv);
    }
    __syncthreads();
    for (int i = t; i < cnt; i += 256) {
        unsigned int s = (unsigned int)srcA[i], d = (unsigned int)dstA[i];
        int p = atomicAdd(&ofs[d >> 9], 1);
        uint2 u; u.x = s; u.y = d;
        buf[p] = u;
    }
    __syncthreads();
    for (int i = t; i < cnt; i += 256) {
        uint2 u = buf[i];
        int b = (int)(u.y >> 9);
        int pos = gbase[b] + (i - excl[b]);
        if (pos < BCAP) pairs[(size_t)(rel*NBKT + b)*BCAP + pos] = u;
    }
}

__global__ void kB_scan(const int* __restrict__ cursor, int* __restrict__ ebase) {
    __shared__ int sc[256];
    const int t = threadIdx.x;
    for (int rel = 0; rel < KK; ++rel) {
        int hv = (t < NBKT) ? min(cursor[rel*NBKT + t], BCAP) : 0;
        sc[t] = hv;
        for (int off = 1; off < 256; off <<= 1) {
            __syncthreads();
            int v = (t >= off) ? sc[t-off] : 0;
            __syncthreads();
            sc[t] += v;
        }
        __syncthreads();
        if (t < NBKT) ebase[rel*NBKT + t] = sc[t] - hv;
        __syncthreads();
    }
}

__global__ void kB_fill(const uint2* __restrict__ pairs, const int* __restrict__ cursor,
                        const int* __restrict__ ebase, int* __restrict__ rp,
                        int* __restrict__ col) {
    __shared__ int h2[512], excl[512], cur[512], sc[256];
    const int b = blockIdx.x, rel = blockIdx.y, t = threadIdx.x;
    const int lo = b * 512;
    const int cnt = min(cursor[rel*NBKT + b], BCAP);
    const int base = ebase[rel*NBKT + b];
    const uint2* P = pairs + (size_t)(rel*NBKT + b)*BCAP;
    h2[t] = 0; h2[t+256] = 0; cur[t] = 0; cur[t+256] = 0;
    __syncthreads();
    for (int i = t; i < cnt; i += 256) atomicAdd(&h2[(int)P[i].y - lo], 1);
    __syncthreads();
    const int a0 = h2[2*t], a1 = h2[2*t+1];
    sc[t] = a0 + a1;
    for (int off = 1; off < 256; off <<= 1) {
        __syncthreads();
        int v = (t >= off) ? sc[t-off] : 0;
        __syncthreads();
        sc[t] += v;
    }
    __syncthreads();
    const int e2 = sc[t] - (a0 + a1);
    excl[2*t] = e2; excl[2*t+1] = e2 + a0;
    __syncthreads();
    for (int tt = t; tt < 512; tt += 256) {
        int n = lo + tt;
        if (n <= NV) rp[(size_t)rel*(NV+1) + n] = base + excl[tt];
    }
    for (int i = t; i < cnt; i += 256) {
        uint2 u = P[i];
        int r = (int)u.y - lo;
        int p = atomicAdd(&cur[r], 1);
        col[(size_t)rel*EE + base + excl[r] + p] = (int)u.x;
    }
}

// Per layer: pack W1/W2 to bf16 MFMA fragments; compute softmax(alpha[l])
__global__ void k_prep(const float* __restrict__ W1, const float* __restrict__ W2,
                       const float* __restrict__ alpha, const int l,
                       unsigned short* __restrict__ w1f, unsigned short* __restrict__ w2f,
                       float* __restrict__ params) {
    int id = blockIdx.x*256 + threadIdx.x;
    if (id == 0) {
        float a0 = alpha[l*KK+0], a1 = alpha[l*KK+1], a2 = alpha[l*KK+2];
        float m = fmaxf(a0, fmaxf(a1, a2));
        float e0 = expf(a0-m), e1 = expf(a1-m), e2 = expf(a2-m);
        float inv = 1.f/(e0+e1+e2);
        params[PA+0] = e0*inv; params[PA+1] = e1*inv; params[PA+2] = e2*inv;
    }
    if (id < 4096) {                       // W1: [128][256]
        int kt = id >> 10, nt = (id >> 6) & 15, lane = id & 63;
        int r = lane & 15, g = lane >> 4;
        const float* Wl = W1 + (size_t)l*DD*D2;
        #pragma unroll
        for (int e = 0; e < 8; ++e) {
            int kk = kt*32 + g*8 + e, c = nt*16 + r;
            w1f[(size_t)id*8 + e] = f2bf(Wl[(size_t)kk*D2 + c]);
        }
    } else if (id < 8192) {                // W2: [256][128]
        int id2 = id - 4096;
        int kt = id2 >> 9, nt = (id2 >> 6) & 7, lane = id2 & 63;
        int r = lane & 15, g = lane >> 4;
        const float* Wl = W2 + (size_t)l*D2*DD;
        #pragma unroll
        for (int e = 0; e < 8; ++e) {
            int kk = kt*32 + g*8 + e, c = nt*16 + r;
            w2f[(size_t)id2*8 + e] = f2bf(Wl[(size_t)kk*DD + c]);
        }
    }
}

// zin_k[n,:] = bf16( (1+eps)*h[n,:] + sum_{j->n,k} h[j,:] )  for all 3 relations.
// One wave per node (n wave-uniform -> SGPR). Neighbor indices preloaded
// coalesced; __shfl broadcast on uniform control flow; invalid lanes point at
// the ZERO row (NV) so the edge loop has no predicates/exec-mask churn.
__global__ void k_gather3(const unsigned short* __restrict__ hb, const int* __restrict__ rp,
                          const int* __restrict__ col, const float* __restrict__ epsp,
                          unsigned short* __restrict__ zin) {
    int gid = blockIdx.x*256 + threadIdx.x;
    int n0 = gid >> 6;
    if (n0 >= NV) return;
    const int n = __builtin_amdgcn_readfirstlane(n0);   // wave-uniform -> SGPR
    const int lane = threadIdx.x & 63;
    const int q = lane >> 4, r = lane & 15;
    const int r16 = r << 4;
    const char* hbase = (const char*)hb;
    const float epsv = 1.0f + epsp[0];
    const uint4v sv = *(const uint4v*)(hbase + (((unsigned)n << 8) + r16));
    int b0[KK], dg[KK], cv[KK];
    #pragma unroll
    for (int k = 0; k < KK; ++k) {
        int a = rp[k*(NV+1) + n];
        int b = rp[k*(NV+1) + n + 1];
        b0[k] = a; dg[k] = b - a;
        cv[k] = (lane < dg[k]) ? col[(size_t)k*EE + a + lane] : NV;  // NV = zero row
    }
    f32x2 acc[KK][4];
    #pragma unroll
    for (int k = 0; k < KK; ++k)
        #pragma unroll
        for (int c = 0; c < 4; ++c) acc[k][c] = (f32x2){0.f, 0.f};
    #pragma unroll
    for (int k = 0; k < KK; ++k) {
        const int dc = min(dg[k], 64);            // wave-uniform bound
        for (int base = 0; base < dc; base += 8) {
            int s0 = __shfl(cv[k], base + q);      // lanes all active; idx <= 63
            int s1 = __shfl(cv[k], base + q + 4);
            uint4v v0 = *(const uint4v*)(hbase + (((unsigned)s0 << 8) + r16));
            uint4v v1 = *(const uint4v*)(hbase + (((unsigned)s1 << 8) + r16));
            #pragma unroll
            for (int c = 0; c < 4; ++c) {
                acc[k][c] += up2(v0[c]);
                acc[k][c] += up2(v1[c]);
            }
        }
        // deg > 64 tail: direct col loads (no cross-lane ops)
        for (int j = b0[k] + 64 + q; j < b0[k] + dg[k]; j += 4) {
            int s0 = col[(size_t)k*EE + j];
            uint4v v0 = *(const uint4v*)(hbase + (((unsigned)s0 << 8) + r16));
            #pragma unroll
            for (int c = 0; c < 4; ++c) acc[k][c] += up2(v0[c]);
        }
    }
    #pragma unroll
    for (int k = 0; k < KK; ++k) {
        #pragma unroll
        for (int c = 0; c < 4; ++c) {
            acc[k][c][0] += __shfl_xor(acc[k][c][0], 16);
            acc[k][c][1] += __shfl_xor(acc[k][c][1], 16);
            acc[k][c][0] += __shfl_xor(acc[k][c][0], 32);
            acc[k][c][1] += __shfl_xor(acc[k][c][1], 32);
        }
    }
    if (q == 0) {
        #pragma unroll
        for (int k = 0; k < KK; ++k) {
            uint4v pk;
            #pragma unroll
            for (int c = 0; c < 4; ++c) {
                f32x2 s2 = up2(sv[c]);
                float lo = acc[k][c][0] + epsv * s2[0];
                float hi = acc[k][c][1] + epsv * s2[1];
                unsigned int pko;
                asm("v_cvt_pk_bf16_f32 %0, %1, %2" : "=v"(pko) : "v"(lo), "v"(hi));
                pk[c] = pko;
            }
            *(uint4v*)((char*)zin + (size_t)k*NV*DD*2 + (((unsigned)n << 8) + r16)) = pk;
        }
    }
}

// BN1 stats of z1_k = zin_k @ W1 for all relations (grid.y = k), z1 never stored.
__launch_bounds__(256, 2)
__global__ void k_stats3(const unsigned short* __restrict__ zin,
                         const unsigned short* __restrict__ w1f,
                         float* __restrict__ stats) {
    __shared__ __align__(16) unsigned short bfr1[32768];  // 64KB W1 frags
    __shared__ float scf[1024];
    const int t = threadIdx.x;
    const int krel = blockIdx.y;
    const unsigned short* zk = zin + (size_t)krel*NV*DD;
    float* zsum = stats + ZS(krel);
    float* zsq  = stats + ZQ(krel);
    for (int i = t; i < 4096; i += 256)
        *(uint4v*)(bfr1 + i*8) = *(const uint4v*)(w1f + i*8);
    const int lane = t & 63, w = t >> 6;
    const int r_ = lane & 15, g = lane >> 4;
    const int rt = w & 1, ch = w >> 1;
    __syncthreads();
    float ssum[8] = {0,0,0,0,0,0,0,0};
    float ssq[8]  = {0,0,0,0,0,0,0,0};
    for (int tile = blockIdx.x; tile < NV/32; tile += gridDim.x) {
        const int row0 = tile*32;
        short8 af[4];
        #pragma unroll
        for (int kt = 0; kt < 4; ++kt)
            af[kt] = *(const short8*)(zk + (size_t)(row0 + rt*16 + r_)*DD + kt*32 + g*8);
        #pragma unroll
        for (int ct = 0; ct < 8; ++ct) {
            const int ntg = ch*8 + ct;
            f32x4 c = {0.f,0.f,0.f,0.f};
            #pragma unroll
            for (int kt = 0; kt < 4; ++kt) {
                short8 b = *(const short8*)(bfr1 + ((size_t)((kt*16 + ntg)*64 + lane))*8);
                c = __builtin_amdgcn_mfma_f32_16x16x32_bf16(af[kt], b, c, 0, 0, 0);
            }
            float s = c[0]+c[1]+c[2]+c[3];
            float q = c[0]*c[0]+c[1]*c[1]+c[2]*c[2]+c[3]*c[3];
            s += __shfl_xor(s, 16); q += __shfl_xor(q, 16);
            s += __shfl_xor(s, 32); q += __shfl_xor(q, 32);
            ssum[ct] += s; ssq[ct] += q;
        }
    }
    if (g == 0) {
        #pragma unroll
        for (int ct = 0; ct < 8; ++ct) {
            const int colc = (ch*8 + ct)*16 + r_;
            scf[rt*256 + colc]       = ssum[ct];
            scf[512 + rt*256 + colc] = ssq[ct];
        }
    }
    __syncthreads();
    atomicAdd(zsum + t, scf[t]       + scf[256 + t]);
    atomicAdd(zsq  + t, scf[512 + t] + scf[768 + t]);
}

// BN1 affine for all 3 relations, a_k folded in (a_k>0: a*relu(u) = relu(a*u))
__global__ void k_bnprep3(float* __restrict__ stats,
                          const float* __restrict__ g1l, const float* __restrict__ be1l,
                          float* __restrict__ params) {
    int j = threadIdx.x;  // 256
    #pragma unroll
    for (int k = 0; k < KK; ++k) {
        float ak  = params[PA + k];
        float mu  = stats[ZS(k) + j] * (1.0f/NV);
        float var = stats[ZQ(k) + j] * (1.0f/NV) - mu*mu;
        float A = g1l[j] * rsqrtf(var + 1e-5f);
        params[PA1K(k) + j] = ak * A;
        params[PB1K(k) + j] = ak * (be1l[j] - mu*A);
        stats[ZS(k) + j] = 0.0f; stats[ZQ(k) + j] = 0.0f;   // re-zero for next layer
    }
}

// hn = [ sum_k relu(A''_k (zin_k @ W1) + B''_k) ] @ W2 + hn column stats.
// R7-proven structure: 8 waves, W1+W2 LDS-resident (128KB), single 16KB yt,
// double-buffered zin REGISTER prefetch (afA/afB), 2 barriers per tile.
#define LOAD_AF(AF, TILE) {                                                        \
    const int rowp_ = (TILE)*32;                                                   \
    _Pragma("unroll")                                                              \
    for (int k = 0; k < KK; ++k) {                                                 \
        _Pragma("unroll")                                                          \
        for (int kt = 0; kt < 4; ++kt)                                             \
            AF[k][kt] = *(const short8*)(zin + (size_t)k*NV*DD                     \
                          + (size_t)(rowp_ + rt*16 + r_)*DD + kt*32 + g*8);        \
    }                                                                              \
}

#define GBODY(AF, AFN) {                                                           \
    const int cur_ = tile, nx_ = tile + step;                                      \
    f32x4 y[4];                                                                    \
    _Pragma("unroll")                                                              \
    for (int ct = 0; ct < 4; ++ct) y[ct] = (f32x4){0.f,0.f,0.f,0.f};               \
    _Pragma("unroll")                                                              \
    for (int k = 0; k < KK; ++k) {                                                 \
        _Pragma("unroll")                                                          \
        for (int ct = 0; ct < 4; ++ct) {                                           \
            const int ntg = ch*4 + ct;                                             \
            f32x4 c = {0.f,0.f,0.f,0.f};                                           \
            _Pragma("unroll")                                                      \
            for (int kt = 0; kt < 4; ++kt) {                                       \
                short8 b = *(const short8*)(bfr1 + ((size_t)((kt*16 + ntg)*64 + lane))*8); \
                c = __builtin_amdgcn_mfma_f32_16x16x32_bf16(AF[k][kt], b, c, 0, 0, 0); \
            }                                                                      \
            _Pragma("unroll")                                                      \
            for (int reg = 0; reg < 4; ++reg)                                      \
                y[ct][reg] += fmaxf(pa1[k][ct]*c[reg] + pb1[k][ct], 0.0f);         \
        }                                                                          \
    }                                                                              \
    if (nx_ < NT) LOAD_AF(AFN, nx_);                                               \
    __syncthreads();                                                               \
    _Pragma("unroll")                                                              \
    for (int ct = 0; ct < 4; ++ct) {                                               \
        const int col2 = ((ch*4 + ct)*16 + r_)*2;                                  \
        _Pragma("unroll")                                                          \
        for (int reg = 0; reg < 4; ++reg) {                                        \
            const int row = rt*16 + g*4 + reg;                                     \
            *(unsigned short*)(yt + row*512 + (col2 ^ ((row & 15) << 4))) = f2bf(y[ct][reg]); \
        }                                                                          \
    }                                                                              \
    __syncthreads();                                                               \
    short8 ya[8];                                                                  \
    _Pragma("unroll")                                                              \
    for (int kt = 0; kt < 8; ++kt)                                                 \
        ya[kt] = *(const short8*)(yt + arow*512 + ((kt*64 + g*16) ^ ((arow & 15) << 4))); \
    _Pragma("unroll")                                                              \
    for (int ct2 = 0; ct2 < 2; ++ct2) {                                            \
        const int ntg2 = ch*2 + ct2;                                               \
        f32x4 c = {0.f,0.f,0.f,0.f};                                               \
        _Pragma("unroll")                                                          \
        for (int kt = 0; kt < 8; ++kt) {                                           \
            short8 b = *(const short8*)(bfr2 + ((size_t)((kt*8 + ntg2)*64 + lane))*8); \
            c = __builtin_amdgcn_mfma_f32_16x16x32_bf16(ya[kt], b, c, 0, 0, 0);    \
        }                                                                          \
        unsigned short* hp = hnb + (size_t)(cur_*32 + rt*16 + g*4)*DD + ntg2*16 + r_; \
        float ps = 0.0f, pq = 0.0f;                                                \
        _Pragma("unroll")                                                          \
        for (int reg = 0; reg < 4; ++reg) {                                        \
            float xv = c[reg];                                                     \
            hp[(size_t)reg*DD] = f2bf(xv);                                         \
            ps += xv; pq += xv*xv;                                                 \
        }                                                                          \
        ps += __shfl_xor(ps, 16); pq += __shfl_xor(pq, 16);                        \
        ps += __shfl_xor(ps, 32); pq += __shfl_xor(pq, 32);                        \
        ssum[ct2] += ps; ssq[ct2] += pq;                                           \
    }                                                                              \
    tile = nx_;                                                                    \
}

__launch_bounds__(512, 2)
__global__ void k_gemm2f(const unsigned short* __restrict__ zin,
                         const unsigned short* __restrict__ w1f,
                         const unsigned short* __restrict__ w2f,
                         const float* __restrict__ params,
                         unsigned short* __restrict__ hnb,
                         float* __restrict__ hsum, float* __restrict__ hsq) {
    __shared__ __align__(16) unsigned short bfr1[32768];  // 64KB W1 frags
    __shared__ __align__(16) unsigned short bfr2[32768];  // 64KB W2 frags
    __shared__ __align__(16) unsigned char yt[16384];     // 32 x 256 bf16, swizzled
    const int t = threadIdx.x;
    for (int i = t; i < 4096; i += 512)
        *(uint4v*)(bfr1 + i*8) = *(const uint4v*)(w1f + i*8);
    for (int i = t; i < 4096; i += 512)
        *(uint4v*)(bfr2 + i*8) = *(const uint4v*)(w2f + i*8);
    const int lane = t & 63, w = t >> 6;          // 8 waves
    const int r_ = lane & 15, g = lane >> 4;
    const int rt = w & 1, ch = w >> 1;            // rt: row half, ch: col quarter
    const int arow = rt*16 + r_;
    float pa1[KK][4], pb1[KK][4];
    #pragma unroll
    for (int k = 0; k < KK; ++k) {
        #pragma unroll
        for (int ct = 0; ct < 4; ++ct) {
            const int colc = (ch*4 + ct)*16 + r_;
            pa1[k][ct] = params[PA1K(k) + colc];
            pb1[k][ct] = params[PB1K(k) + colc];
        }
    }
    __syncthreads();
    float ssum[2] = {0,0}, ssq[2] = {0,0};
    const int NT = NV/32;
    const int step = gridDim.x;
    int tile = blockIdx.x;
    short8 afA[KK][4], afB[KK][4];
    LOAD_AF(afA, tile);
    while (tile < NT) {
        GBODY(afA, afB);
        if (tile >= NT) break;
        GBODY(afB, afA);
    }
    // flush hn column stats (reuse yt; wave w covers cols ch*32 .. ch*32+31)
    __syncthreads();
    float* scf = (float*)yt;
    if (g == 0) {
        #pragma unroll
        for (int ct2 = 0; ct2 < 2; ++ct2) {
            scf[w*32 + ct2*16 + r_]       = ssum[ct2];
            scf[256 + w*32 + ct2*16 + r_] = ssq[ct2];
        }
    }
    __syncthreads();
    if (t < 128) {
        const int chc = t >> 5, idx = t & 31;
        float s = 0.0f, q = 0.0f;
        #pragma unroll
        for (int rr = 0; rr < 2; ++rr) {
            s += scf[(chc*2 + rr)*32 + idx];
            q += scf[256 + (chc*2 + rr)*32 + idx];
        }
        atomicAdd(hsum + t, s);
        atomicAdd(hsq + t, q);
    }
}

__global__ void k_bnprep2(float* __restrict__ hsum, float* __restrict__ hsq,
                          const float* __restrict__ bng, const float* __restrict__ bnb,
                          float* __restrict__ params) {
    int j = threadIdx.x;  // 128
    float mu  = hsum[j] * (1.0f/NV);
    float var = hsq[j]  * (1.0f/NV) - mu*mu;
    float A = bng[j] * rsqrtf(var + 1e-5f);
    params[PA2 + j] = A;
    params[PB2 + j] = bnb[j] - mu*A;
    hsum[j] = 0.0f; hsq[j] = 0.0f;
}

// mid layers: h(bf16) = relu(BN2(hn))
__global__ void k_bnapply_mid(const unsigned short* __restrict__ hnb,
                              const float* __restrict__ params,
                              unsigned short* __restrict__ hb) {
    int id = blockIdx.x*256 + threadIdx.x;       // 6250 blocks * 8 elems
    const int col0 = (id & 15)*8;
    short8 v = *(const short8*)(hnb + (size_t)id*8);
    f32x4 A0 = *(const f32x4*)(params + PA2 + col0);
    f32x4 A1 = *(const f32x4*)(params + PA2 + col0 + 4);
    f32x4 B0 = *(const f32x4*)(params + PB2 + col0);
    f32x4 B1 = *(const f32x4*)(params + PB2 + col0 + 4);
    short8 o;
    #pragma unroll
    for (int j = 0; j < 4; ++j) {
        o[j]   = (short)f2bf(fmaxf(A0[j]*bf2f((unsigned short)v[j])   + B0[j], 0.0f));
        o[j+4] = (short)f2bf(fmaxf(A1[j]*bf2f((unsigned short)v[j+4]) + B1[j], 0.0f));
    }
    *(short8*)(hb + (size_t)id*8) = o;
}

// final layer: d_out(f32) = relu(BN2(hn))
__global__ void k_bnapply_fin(const unsigned short* __restrict__ hnb,
                              const float* __restrict__ params,
                              float* __restrict__ out) {
    int id = blockIdx.x*256 + threadIdx.x;
    const int col0 = (id & 15)*8;
    short8 v = *(const short8*)(hnb + (size_t)id*8);
    f32x4 A0 = *(const f32x4*)(params + PA2 + col0);
    f32x4 A1 = *(const f32x4*)(params + PA2 + col0 + 4);
    f32x4 B0 = *(const f32x4*)(params + PB2 + col0);
    f32x4 B1 = *(const f32x4*)(params + PB2 + col0 + 4);
    f32x4 o0, o1;
    #pragma unroll
    for (int j = 0; j < 4; ++j) {
        o0[j] = fmaxf(A0[j]*bf2f((unsigned short)v[j])   + B0[j], 0.0f);
        o1[j] = fmaxf(A1[j]*bf2f((unsigned short)v[j+4]) + B1[j], 0.0f);
    }
    *(f32x4*)(out + (size_t)id*8)     = o0;
    *(f32x4*)(out + (size_t)id*8 + 4) = o1;
}

extern "C" void kernel_launch(void* const* d_in, const int* in_sizes, int n_in,
                              void* d_out, int out_size, void* d_ws, size_t ws_size,
                              hipStream_t stream) {
    const int*   x     = (const int*)d_in[0];
    const int*   ke    = (const int*)d_in[1];
    const float* emb   = (const float*)d_in[2];
    const float* W1    = (const float*)d_in[3];
    // d_in[4] = b1: per-column shift cancels exactly through training-mode BN
    const float* g1    = (const float*)d_in[5];
    const float* be1   = (const float*)d_in[6];
    const float* W2    = (const float*)d_in[7];
    // d_in[8] = b2: cancels through final BN (softmax weights sum to 1)
    const float* eps   = (const float*)d_in[9];
    const float* alpha = (const float*)d_in[10];
    const float* bng   = (const float*)d_in[11];
    const float* bnb   = (const float*)d_in[12];

    char* ws = (char*)d_ws;
    unsigned short* hb     = (unsigned short*)(ws + HB_OFF);
    unsigned short* zin    = (unsigned short*)(ws + ZIN_OFF);   // 3 buffers
    unsigned short* hnb    = (unsigned short*)(ws + HNB_OFF);
    size_t o = O_BASE;
    unsigned short* w1f    = (unsigned short*)(ws + o);          o += 65536;
    unsigned short* w2f    = (unsigned short*)(ws + o);          o += 65536;
    float*          stats  = (float*)(ws + o);                   o += 8192;
    float*          params = (float*)(ws + o);                   o += 8192;
    int*            rp     = (int*)(ws + o);                     o += 1200128;
    int*            col    = (int*)(ws + o);                     o += 7200000;
    int*            cur    = (int*)(ws + o);                     o += 4096;
    int*            ebase  = (int*)(ws + o);                     o += 4096;
    uint2*          pairs  = (uint2*)(ws + ZIN_OFF);             // aliased (pre-zin)

    // AtomEncoder (+ zero-pad rows NV..NV+7 for the gather dummy row)
    k_embed<<<12501, 256, 0, stream>>>(x, emb, hb);

    // CSR build (shared by all layers; uses pairs alias before any zin write)
    hipMemsetAsync(cur, 0, KK*NBKT*sizeof(int), stream);
    hipMemsetAsync(stats, 0, 8192, stream);
    kA_bin<<<dim3(147, KK), 256, 0, stream>>>(ke, cur, pairs);
    kB_scan<<<1, 256, 0, stream>>>(cur, ebase);
    kB_fill<<<dim3(NBKT, KK), 256, 0, stream>>>(pairs, cur, ebase, rp, col);

    for (int l = 0; l < LL; ++l) {
        k_prep<<<32, 256, 0, stream>>>(W1, W2, alpha, l, w1f, w2f, params);
        k_gather3<<<25000, 256, 0, stream>>>(hb, rp, col, eps + l, zin);
        k_stats3<<<dim3(512, KK), 256, 0, stream>>>(zin, w1f, stats);
        k_bnprep3<<<1, 256, 0, stream>>>(stats, g1 + l*D2, be1 + l*D2, params);
        k_gemm2f<<<256, 512, 0, stream>>>(zin, w1f, w2f, params, hnb,
                                          stats + HSUM, stats + HSQ);
        k_bnprep2<<<1, 128, 0, stream>>>(stats + HSUM, stats + HSQ,
                                         bng + l*DD, bnb + l*DD, params);
        if (l < LL-1) k_bnapply_mid<<<6250, 256, 0, stream>>>(hnb, params, hb);
        else          k_bnapply_fin<<<6250, 256, 0, stream>>>(hnb, params, (float*)d_out);
    }
}

// Round 13
// 723.212 us; speedup vs baseline: 1.2022x; 1.0372x over previous
//
#include <hip/hip_runtime.h>

// Problem constants (match reference setup_inputs)
#define NV     100000   // nodes
#define DD     128      // hidden dim
#define D2     256      // 2*D
#define EE     600000   // edges per relation
#define KK     3        // relations
#define LL     3        // layers
#define NFEAT  9
#define VOCABS 100

#define NBKT   196      // CSR buckets per relation (512 nodes each)
#define BCAP   8192     // bucket capacity (mean 3061, sigma 55 -> never hit)

typedef __attribute__((ext_vector_type(8))) short short8;
typedef __attribute__((ext_vector_type(4))) float f32x4;
typedef __attribute__((ext_vector_type(2))) float f32x2;
typedef __attribute__((ext_vector_type(4))) unsigned int uint4v;

// params layout (float offsets)
#define PA      0                      // a[3] = softmax(alpha[l])

// per-layer stats region (float offsets within stats + l*2048):
//   ZS(k)=k*512 zsum[256]; ZQ(k)=k*512+256 zsq[256]; HSUM=1536; HSQ=1664
#define ZS(k)  ((k)*512)
#define ZQ(k)  ((k)*512 + 256)
#define HSUM   1536
#define HSQ    1664

// workspace byte offsets (hb padded by 8 zero rows -> zero-row gather trick)
#define HB_OFF   ((size_t)0)            // h (bf16)     (N+8)*128
#define ZIN_OFF  ((size_t)25700000)     // zin_k (bf16) 3 x N*128 ; CSR pairs aliased
#define HNB_OFF  ((size_t)102500000)    // h_next (bf16) N*128
#define O_BASE   ((size_t)128100000)

__device__ __forceinline__ unsigned short f2bf(float f) {
    union { float f; unsigned int u; } v; v.f = f;
    return (unsigned short)((v.u + 0x7FFFu + ((v.u >> 16) & 1u)) >> 16);
}
__device__ __forceinline__ float bf2f(unsigned short u) {
    union { unsigned int u; float f; } v; v.u = ((unsigned int)u) << 16;
    return v.f;
}
// unpack a bf16 pair (one u32) to f32x2 {lo, hi}
__device__ __forceinline__ f32x2 up2(unsigned int v) {
    union { unsigned int u[2]; f32x2 f; } w;
    w.u[0] = v << 16;
    w.u[1] = v & 0xFFFF0000u;
    return w.f;
}

// h[n,d] = sum_f emb[f, x[n,f], d] -> bf16 ; rows NV..NV+7 zeroed (gather dummy)
__global__ void k_embed(const int* __restrict__ x, const float* __restrict__ emb,
                        unsigned short* __restrict__ hb) {
    int id = blockIdx.x*256 + threadIdx.x;
    int n = id >> 5, q = id & 31;
    if (n >= NV) {
        if (n < NV + 8) *(unsigned long long*)(hb + (size_t)n*DD + q*4) = 0ull;
        return;
    }
    const int* xr = x + n*NFEAT;
    f32x4 acc = {0.f,0.f,0.f,0.f};
    #pragma unroll
    for (int f = 0; f < NFEAT; ++f) {
        int idx = xr[f];
        acc += *(const f32x4*)(emb + ((size_t)(f*VOCABS + idx)*DD + q*4));
    }
    unsigned short pk[4];
    pk[0] = f2bf(acc[0]); pk[1] = f2bf(acc[1]); pk[2] = f2bf(acc[2]); pk[3] = f2bf(acc[3]);
    *(unsigned long long*)(hb + (size_t)n*DD + q*4) = *(unsigned long long*)pk;
}

// ---- CSR build: radix-binned, write-amplification-free ----
__global__ void kA_bin(const int* __restrict__ ke, int* __restrict__ cursor,
                       uint2* __restrict__ pairs) {
    __shared__ int hist[NBKT], excl[NBKT], ofs[NBKT], gbase[NBKT];
    __shared__ int sc[256];
    __shared__ uint2 buf[4096];
    const int rel = blockIdx.y, t = threadIdx.x;
    const int e0 = blockIdx.x * 4096;
    const int cnt = min(4096, EE - e0);
    const int* srcA = ke + (size_t)(rel*2)*EE + e0;
    const int* dstA = ke + (size_t)(rel*2+1)*EE + e0;
    if (t < NBKT) hist[t] = 0;
    __syncthreads();
    for (int i = t; i < cnt; i += 256) atomicAdd(&hist[dstA[i] >> 9], 1);
    __syncthreads();
    const int hv = (t < NBKT) ? hist[t] : 0;
    sc[t] = hv;
    for (int off = 1; off < 256; off <<= 1) {
        __syncthreads();
        int v = (t >= off) ? sc[t-off] : 0;
        __syncthreads();
        sc[t] += v;
    }
    __syncthreads();
    if (t < NBKT) {
        excl[t] = sc[t] - hv;
        ofs[t]  = sc[t] - hv;
        if (hv > 0) gbase[t] = atomicAdd(&cursor[rel*NBKT + t], hv);
    }
    __syncthreads();
    for (int i = t; i < cnt; i += 256) {
        unsigned int s = (unsigned int)srcA[i], d = (unsigned int)dstA[i];
        int p = atomicAdd(&ofs[d >> 9], 1);
        uint2 u; u.x = s; u.y = d;
        buf[p] = u;
    }
    __syncthreads();
    for (int i = t; i < cnt; i += 256) {
        uint2 u = buf[i];
        int b = (int)(u.y >> 9);
        int pos = gbase[b] + (i - excl[b]);
        if (pos < BCAP) pairs[(size_t)(rel*NBKT + b)*BCAP + pos] = u;
    }
}

__global__ void kB_scan(const int* __restrict__ cursor, int* __restrict__ ebase) {
    __shared__ int sc[256];
    const int t = threadIdx.x;
    for (int rel = 0; rel < KK; ++rel) {
        int hv = (t < NBKT) ? min(cursor[rel*NBKT + t], BCAP) : 0;
        sc[t] = hv;
        for (int off = 1; off < 256; off <<= 1) {
            __syncthreads();
            int v = (t >= off) ? sc[t-off] : 0;
            __syncthreads();
            sc[t] += v;
        }
        __syncthreads();
        if (t < NBKT) ebase[rel*NBKT + t] = sc[t] - hv;
        __syncthreads();
    }
}

__global__ void kB_fill(const uint2* __restrict__ pairs, const int* __restrict__ cursor,
                        const int* __restrict__ ebase, int* __restrict__ rp,
                        int* __restrict__ col) {
    __shared__ int h2[512], excl[512], cur[512], sc[256];
    const int b = blockIdx.x, rel = blockIdx.y, t = threadIdx.x;
    const int lo = b * 512;
    const int cnt = min(cursor[rel*NBKT + b], BCAP);
    const int base = ebase[rel*NBKT + b];
    const uint2* P = pairs + (size_t)(rel*NBKT + b)*BCAP;
    h2[t] = 0; h2[t+256] = 0; cur[t] = 0; cur[t+256] = 0;
    __syncthreads();
    for (int i = t; i < cnt; i += 256) atomicAdd(&h2[(int)P[i].y - lo], 1);
    __syncthreads();
    const int a0 = h2[2*t], a1 = h2[2*t+1];
    sc[t] = a0 + a1;
    for (int off = 1; off < 256; off <<= 1) {
        __syncthreads();
        int v = (t >= off) ? sc[t-off] : 0;
        __syncthreads();
        sc[t] += v;
    }
    __syncthreads();
    const int e2 = sc[t] - (a0 + a1);
    excl[2*t] = e2; excl[2*t+1] = e2 + a0;
    __syncthreads();
    for (int tt = t; tt < 512; tt += 256) {
        int n = lo + tt;
        if (n <= NV) rp[(size_t)rel*(NV+1) + n] = base + excl[tt];
    }
    for (int i = t; i < cnt; i += 256) {
        uint2 u = P[i];
        int r = (int)u.y - lo;
        int p = atomicAdd(&cur[r], 1);
        col[(size_t)rel*EE + base + excl[r] + p] = (int)u.x;
    }
}

// Per layer: pack W1/W2 to bf16 MFMA fragments; compute softmax(alpha[l])
__global__ void k_prep(const float* __restrict__ W1, const float* __restrict__ W2,
                       const float* __restrict__ alpha, const int l,
                       unsigned short* __restrict__ w1f, unsigned short* __restrict__ w2f,
                       float* __restrict__ params) {
    int id = blockIdx.x*256 + threadIdx.x;
    if (id == 0) {
        float a0 = alpha[l*KK+0], a1 = alpha[l*KK+1], a2 = alpha[l*KK+2];
        float m = fmaxf(a0, fmaxf(a1, a2));
        float e0 = expf(a0-m), e1 = expf(a1-m), e2 = expf(a2-m);
        float inv = 1.f/(e0+e1+e2);
        params[PA+0] = e0*inv; params[PA+1] = e1*inv; params[PA+2] = e2*inv;
    }
    if (id < 4096) {                       // W1: [128][256]
        int kt = id >> 10, nt = (id >> 6) & 15, lane = id & 63;
        int r = lane & 15, g = lane >> 4;
        const float* Wl = W1 + (size_t)l*DD*D2;
        #pragma unroll
        for (int e = 0; e < 8; ++e) {
            int kk = kt*32 + g*8 + e, c = nt*16 + r;
            w1f[(size_t)id*8 + e] = f2bf(Wl[(size_t)kk*D2 + c]);
        }
    } else if (id < 8192) {                // W2: [256][128]
        int id2 = id - 4096;
        int kt = id2 >> 9, nt = (id2 >> 6) & 7, lane = id2 & 63;
        int r = lane & 15, g = lane >> 4;
        const float* Wl = W2 + (size_t)l*D2*DD;
        #pragma unroll
        for (int e = 0; e < 8; ++e) {
            int kk = kt*32 + g*8 + e, c = nt*16 + r;
            w2f[(size_t)id2*8 + e] = f2bf(Wl[(size_t)kk*DD + c]);
        }
    }
}

// zin_k[n,:] = bf16( (1+eps)*h[n,:] + sum_{j->n,k} h[j,:] )  for all 3 relations.
// One wave per node (n wave-uniform -> SGPR). Neighbor indices preloaded
// coalesced; __shfl broadcast on uniform control flow; invalid lanes point at
// the ZERO row (NV) so the edge loop has no predicates/exec-mask churn.
__global__ void k_gather3(const unsigned short* __restrict__ hb, const int* __restrict__ rp,
                          const int* __restrict__ col, const float* __restrict__ epsp,
                          unsigned short* __restrict__ zin) {
    int gid = blockIdx.x*256 + threadIdx.x;
    int n0 = gid >> 6;
    if (n0 >= NV) return;
    const int n = __builtin_amdgcn_readfirstlane(n0);   // wave-uniform -> SGPR
    const int lane = threadIdx.x & 63;
    const int q = lane >> 4, r = lane & 15;
    const int r16 = r << 4;
    const char* hbase = (const char*)hb;
    const float epsv = 1.0f + epsp[0];
    const uint4v sv = *(const uint4v*)(hbase + (((unsigned)n << 8) + r16));
    int b0[KK], dg[KK], cv[KK];
    #pragma unroll
    for (int k = 0; k < KK; ++k) {
        int a = rp[k*(NV+1) + n];
        int b = rp[k*(NV+1) + n + 1];
        b0[k] = a; dg[k] = b - a;
        cv[k] = (lane < dg[k]) ? col[(size_t)k*EE + a + lane] : NV;  // NV = zero row
    }
    f32x2 acc[KK][4];
    #pragma unroll
    for (int k = 0; k < KK; ++k)
        #pragma unroll
        for (int c = 0; c < 4; ++c) acc[k][c] = (f32x2){0.f, 0.f};
    #pragma unroll
    for (int k = 0; k < KK; ++k) {
        const int dc = min(dg[k], 64);            // wave-uniform bound
        for (int base = 0; base < dc; base += 8) {
            int s0 = __shfl(cv[k], base + q);      // lanes all active; idx <= 63
            int s1 = __shfl(cv[k], base + q + 4);
            uint4v v0 = *(const uint4v*)(hbase + (((unsigned)s0 << 8) + r16));
            uint4v v1 = *(const uint4v*)(hbase + (((unsigned)s1 << 8) + r16));
            #pragma unroll
            for (int c = 0; c < 4; ++c) {
                acc[k][c] += up2(v0[c]);
                acc[k][c] += up2(v1[c]);
            }
        }
        // deg > 64 tail: direct col loads (no cross-lane ops)
        for (int j = b0[k] + 64 + q; j < b0[k] + dg[k]; j += 4) {
            int s0 = col[(size_t)k*EE + j];
            uint4v v0 = *(const uint4v*)(hbase + (((unsigned)s0 << 8) + r16));
            #pragma unroll
            for (int c = 0; c < 4; ++c) acc[k][c] += up2(v0[c]);
        }
    }
    #pragma unroll
    for (int k = 0; k < KK; ++k) {
        #pragma unroll
        for (int c = 0; c < 4; ++c) {
            acc[k][c][0] += __shfl_xor(acc[k][c][0], 16);
            acc[k][c][1] += __shfl_xor(acc[k][c][1], 16);
            acc[k][c][0] += __shfl_xor(acc[k][c][0], 32);
            acc[k][c][1] += __shfl_xor(acc[k][c][1], 32);
        }
    }
    if (q == 0) {
        #pragma unroll
        for (int k = 0; k < KK; ++k) {
            uint4v pk;
            #pragma unroll
            for (int c = 0; c < 4; ++c) {
                f32x2 s2 = up2(sv[c]);
                float lo = acc[k][c][0] + epsv * s2[0];
                float hi = acc[k][c][1] + epsv * s2[1];
                unsigned int pko;
                asm("v_cvt_pk_bf16_f32 %0, %1, %2" : "=v"(pko) : "v"(lo), "v"(hi));
                pk[c] = pko;
            }
            *(uint4v*)((char*)zin + (size_t)k*NV*DD*2 + (((unsigned)n << 8) + r16)) = pk;
        }
    }
}

// BN1 stats of z1_k = zin_k @ W1 for all relations (grid.y = k), z1 never stored.
__launch_bounds__(256, 2)
__global__ void k_stats3(const unsigned short* __restrict__ zin,
                         const unsigned short* __restrict__ w1f,
                         float* __restrict__ statsL) {
    __shared__ __align__(16) unsigned short bfr1[32768];  // 64KB W1 frags
    __shared__ float scf[1024];
    const int t = threadIdx.x;
    const int krel = blockIdx.y;
    const unsigned short* zk = zin + (size_t)krel*NV*DD;
    float* zsum = statsL + ZS(krel);
    float* zsq  = statsL + ZQ(krel);
    for (int i = t; i < 4096; i += 256)
        *(uint4v*)(bfr1 + i*8) = *(const uint4v*)(w1f + i*8);
    const int lane = t & 63, w = t >> 6;
    const int r_ = lane & 15, g = lane >> 4;
    const int rt = w & 1, ch = w >> 1;
    __syncthreads();
    float ssum[8] = {0,0,0,0,0,0,0,0};
    float ssq[8]  = {0,0,0,0,0,0,0,0};
    for (int tile = blockIdx.x; tile < NV/32; tile += gridDim.x) {
        const int row0 = tile*32;
        short8 af[4];
        #pragma unroll
        for (int kt = 0; kt < 4; ++kt)
            af[kt] = *(const short8*)(zk + (size_t)(row0 + rt*16 + r_)*DD + kt*32 + g*8);
        #pragma unroll
        for (int ct = 0; ct < 8; ++ct) {
            const int ntg = ch*8 + ct;
            f32x4 c = {0.f,0.f,0.f,0.f};
            #pragma unroll
            for (int kt = 0; kt < 4; ++kt) {
                short8 b = *(const short8*)(bfr1 + ((size_t)((kt*16 + ntg)*64 + lane))*8);
                c = __builtin_amdgcn_mfma_f32_16x16x32_bf16(af[kt], b, c, 0, 0, 0);
            }
            float s = c[0]+c[1]+c[2]+c[3];
            float q = c[0]*c[0]+c[1]*c[1]+c[2]*c[2]+c[3]*c[3];
            s += __shfl_xor(s, 16); q += __shfl_xor(q, 16);
            s += __shfl_xor(s, 32); q += __shfl_xor(q, 32);
            ssum[ct] += s; ssq[ct] += q;
        }
    }
    if (g == 0) {
        #pragma unroll
        for (int ct = 0; ct < 8; ++ct) {
            const int colc = (ch*8 + ct)*16 + r_;
            scf[rt*256 + colc]       = ssum[ct];
            scf[512 + rt*256 + colc] = ssq[ct];
        }
    }
    __syncthreads();
    atomicAdd(zsum + t, scf[t]       + scf[256 + t]);
    atomicAdd(zsq  + t, scf[512 + t] + scf[768 + t]);
}

// hn = [ sum_k relu(A''_k (zin_k @ W1) + B''_k) ] @ W2 + hn column stats.
// R5-proven structure: 8 waves, W1+W2 LDS-resident (128KB), single 16KB yt,
// NO register prefetch (R8/R12 showed it spills: VGPR 88 here vs 128+spill).
// BN1 affine computed inline from raw stats (replaces k_bnprep3).
__launch_bounds__(512, 2)
__global__ void k_gemm2f(const unsigned short* __restrict__ zin,
                         const unsigned short* __restrict__ w1f,
                         const unsigned short* __restrict__ w2f,
                         const float* __restrict__ g1l, const float* __restrict__ be1l,
                         const float* __restrict__ params,
                         float* __restrict__ statsL,
                         unsigned short* __restrict__ hnb) {
    __shared__ __align__(16) unsigned short bfr1[32768];  // 64KB W1 frags
    __shared__ __align__(16) unsigned short bfr2[32768];  // 64KB W2 frags
    __shared__ __align__(16) unsigned char yt[16384];     // 32 x 256 bf16, swizzled
    const int t = threadIdx.x;
    for (int i = t; i < 4096; i += 512)
        *(uint4v*)(bfr1 + i*8) = *(const uint4v*)(w1f + i*8);
    for (int i = t; i < 4096; i += 512)
        *(uint4v*)(bfr2 + i*8) = *(const uint4v*)(w2f + i*8);
    const int lane = t & 63, w = t >> 6;          // 8 waves
    const int r_ = lane & 15, g = lane >> 4;
    const int rt = w & 1, ch = w >> 1;            // rt: row half, ch: col quarter
    const int arow = rt*16 + r_;
    // BN1 affine (a_k folded) computed inline from raw column stats
    float pa1[KK][4], pb1[KK][4];
    #pragma unroll
    for (int k = 0; k < KK; ++k) {
        const float ak = params[PA + k];
        #pragma unroll
        for (int ct = 0; ct < 4; ++ct) {
            const int colc = (ch*4 + ct)*16 + r_;
            float mu  = statsL[ZS(k) + colc] * (1.0f/NV);
            float var = statsL[ZQ(k) + colc] * (1.0f/NV) - mu*mu;
            float A = g1l[colc] * rsqrtf(var + 1e-5f);
            pa1[k][ct] = ak * A;
            pb1[k][ct] = ak * (be1l[colc] - mu*A);
        }
    }
    __syncthreads();
    float ssum[2] = {0,0}, ssq[2] = {0,0};
    for (int tile = blockIdx.x; tile < NV/32; tile += gridDim.x) {
        const int row0 = tile*32;
        // phase 1: y = sum_k relu(BN1_k(zin_k @ W1)); af loaded inline
        f32x4 y[4];
        #pragma unroll
        for (int ct = 0; ct < 4; ++ct) y[ct] = (f32x4){0.f,0.f,0.f,0.f};
        short8 af[KK][4];
        #pragma unroll
        for (int k = 0; k < KK; ++k) {
            #pragma unroll
            for (int kt = 0; kt < 4; ++kt)
                af[k][kt] = *(const short8*)(zin + (size_t)k*NV*DD
                              + (size_t)(row0 + rt*16 + r_)*DD + kt*32 + g*8);
        }
        #pragma unroll
        for (int k = 0; k < KK; ++k) {
            #pragma unroll
            for (int ct = 0; ct < 4; ++ct) {
                const int ntg = ch*4 + ct;
                f32x4 c = {0.f,0.f,0.f,0.f};
                #pragma unroll
                for (int kt = 0; kt < 4; ++kt) {
                    short8 b = *(const short8*)(bfr1 + ((size_t)((kt*16 + ntg)*64 + lane))*8);
                    c = __builtin_amdgcn_mfma_f32_16x16x32_bf16(af[k][kt], b, c, 0, 0, 0);
                }
                #pragma unroll
                for (int reg = 0; reg < 4; ++reg)
                    y[ct][reg] += fmaxf(pa1[k][ct]*c[reg] + pb1[k][ct], 0.0f);
            }
        }
        __syncthreads();   // prev phase2 done reading yt
        #pragma unroll
        for (int ct = 0; ct < 4; ++ct) {
            const int col2 = ((ch*4 + ct)*16 + r_)*2;
            #pragma unroll
            for (int reg = 0; reg < 4; ++reg) {
                const int row = rt*16 + g*4 + reg;
                *(unsigned short*)(yt + row*512 + (col2 ^ ((row & 15) << 4))) = f2bf(y[ct][reg]);
            }
        }
        __syncthreads();
        // phase 2: hn = y @ W2 (W2 from LDS)
        short8 ya[8];
        #pragma unroll
        for (int kt = 0; kt < 8; ++kt)
            ya[kt] = *(const short8*)(yt + arow*512 + ((kt*64 + g*16) ^ ((arow & 15) << 4)));
        #pragma unroll
        for (int ct2 = 0; ct2 < 2; ++ct2) {
            const int ntg2 = ch*2 + ct2;
            f32x4 c = {0.f,0.f,0.f,0.f};
            #pragma unroll
            for (int kt = 0; kt < 8; ++kt) {
                short8 b = *(const short8*)(bfr2 + ((size_t)((kt*8 + ntg2)*64 + lane))*8);
                c = __builtin_amdgcn_mfma_f32_16x16x32_bf16(ya[kt], b, c, 0, 0, 0);
            }
            unsigned short* hp = hnb + (size_t)(row0 + rt*16 + g*4)*DD + ntg2*16 + r_;
            float ps = 0.0f, pq = 0.0f;
            #pragma unroll
            for (int reg = 0; reg < 4; ++reg) {
                float xv = c[reg];
                hp[(size_t)reg*DD] = f2bf(xv);
                ps += xv; pq += xv*xv;
            }
            ps += __shfl_xor(ps, 16); pq += __shfl_xor(pq, 16);
            ps += __shfl_xor(ps, 32); pq += __shfl_xor(pq, 32);
            ssum[ct2] += ps; ssq[ct2] += pq;
        }
    }
    // flush hn column stats (reuse yt; wave w covers cols ch*32 .. ch*32+31)
    __syncthreads();
    float* scf = (float*)yt;
    if (g == 0) {
        #pragma unroll
        for (int ct2 = 0; ct2 < 2; ++ct2) {
            scf[w*32 + ct2*16 + r_]       = ssum[ct2];
            scf[256 + w*32 + ct2*16 + r_] = ssq[ct2];
        }
    }
    __syncthreads();
    if (t < 128) {
        const int chc = t >> 5, idx = t & 31;
        float s = 0.0f, q = 0.0f;
        #pragma unroll
        for (int rr = 0; rr < 2; ++rr) {
            s += scf[(chc*2 + rr)*32 + idx];
            q += scf[256 + (chc*2 + rr)*32 + idx];
        }
        atomicAdd(statsL + HSUM + t, s);
        atomicAdd(statsL + HSQ + t, q);
    }
}

// mid layers: h(bf16) = relu(BN2(hn)); BN2 affine computed inline from stats
__global__ void k_bnapply_mid(const unsigned short* __restrict__ hnb,
                              const float* __restrict__ statsL,
                              const float* __restrict__ bng, const float* __restrict__ bnb,
                              unsigned short* __restrict__ hb) {
    int id = blockIdx.x*256 + threadIdx.x;       // 6250 blocks * 8 elems
    const int col0 = (id & 15)*8;
    short8 v = *(const short8*)(hnb + (size_t)id*8);
    short8 o;
    #pragma unroll
    for (int j = 0; j < 8; ++j) {
        const int c = col0 + j;
        float mu  = statsL[HSUM + c] * (1.0f/NV);
        float var = statsL[HSQ + c] * (1.0f/NV) - mu*mu;
        float A = bng[c] * rsqrtf(var + 1e-5f);
        float B = bnb[c] - mu*A;
        o[j] = (short)f2bf(fmaxf(A*bf2f((unsigned short)v[j]) + B, 0.0f));
    }
    *(short8*)(hb + (size_t)id*8) = o;
}

// final layer: d_out(f32) = relu(BN2(hn))
__global__ void k_bnapply_fin(const unsigned short* __restrict__ hnb,
                              const float* __restrict__ statsL,
                              const float* __restrict__ bng, const float* __restrict__ bnb,
                              float* __restrict__ out) {
    int id = blockIdx.x*256 + threadIdx.x;
    const int col0 = (id & 15)*8;
    short8 v = *(const short8*)(hnb + (size_t)id*8);
    f32x4 o0, o1;
    #pragma unroll
    for (int j = 0; j < 8; ++j) {
        const int c = col0 + j;
        float mu  = statsL[HSUM + c] * (1.0f/NV);
        float var = statsL[HSQ + c] * (1.0f/NV) - mu*mu;
        float A = bng[c] * rsqrtf(var + 1e-5f);
        float B = bnb[c] - mu*A;
        float r = fmaxf(A*bf2f((unsigned short)v[j]) + B, 0.0f);
        if (j < 4) o0[j] = r; else o1[j-4] = r;
    }
    *(f32x4*)(out + (size_t)id*8)     = o0;
    *(f32x4*)(out + (size_t)id*8 + 4) = o1;
}

extern "C" void kernel_launch(void* const* d_in, const int* in_sizes, int n_in,
                              void* d_out, int out_size, void* d_ws, size_t ws_size,
                              hipStream_t stream) {
    const int*   x     = (const int*)d_in[0];
    const int*   ke    = (const int*)d_in[1];
    const float* emb   = (const float*)d_in[2];
    const float* W1    = (const float*)d_in[3];
    // d_in[4] = b1: per-column shift cancels exactly through training-mode BN
    const float* g1    = (const float*)d_in[5];
    const float* be1   = (const float*)d_in[6];
    const float* W2    = (const float*)d_in[7];
    // d_in[8] = b2: cancels through final BN (softmax weights sum to 1)
    const float* eps   = (const float*)d_in[9];
    const float* alpha = (const float*)d_in[10];
    const float* bng   = (const float*)d_in[11];
    const float* bnb   = (const float*)d_in[12];

    char* ws = (char*)d_ws;
    unsigned short* hb     = (unsigned short*)(ws + HB_OFF);
    unsigned short* zin    = (unsigned short*)(ws + ZIN_OFF);   // 3 buffers
    unsigned short* hnb    = (unsigned short*)(ws + HNB_OFF);
    size_t o = O_BASE;
    unsigned short* w1f    = (unsigned short*)(ws + o);          o += 65536;
    unsigned short* w2f    = (unsigned short*)(ws + o);          o += 65536;
    float*          stats  = (float*)(ws + o);                   o += 32768;  // 3 x 2048 floats
    float*          params = (float*)(ws + o);                   o += 4096;
    int*            rp     = (int*)(ws + o);                     o += 1200128;
    int*            col    = (int*)(ws + o);                     o += 7200000;
    int*            cur    = (int*)(ws + o);                     o += 4096;
    int*            ebase  = (int*)(ws + o);                     o += 4096;
    uint2*          pairs  = (uint2*)(ws + ZIN_OFF);             // aliased (pre-zin)

    // AtomEncoder (+ zero-pad rows NV..NV+7 for the gather dummy row)
    k_embed<<<12501, 256, 0, stream>>>(x, emb, hb);

    // CSR build (shared by all layers; uses pairs alias before any zin write)
    hipMemsetAsync(cur, 0, KK*NBKT*sizeof(int), stream);
    hipMemsetAsync(stats, 0, 3*2048*sizeof(float), stream);   // all layers' stats
    kA_bin<<<dim3(147, KK), 256, 0, stream>>>(ke, cur, pairs);
    kB_scan<<<1, 256, 0, stream>>>(cur, ebase);
    kB_fill<<<dim3(NBKT, KK), 256, 0, stream>>>(pairs, cur, ebase, rp, col);

    for (int l = 0; l < LL; ++l) {
        float* statsL = stats + (size_t)l*2048;
        k_prep<<<32, 256, 0, stream>>>(W1, W2, alpha, l, w1f, w2f, params);
        k_gather3<<<25000, 256, 0, stream>>>(hb, rp, col, eps + l, zin);
        k_stats3<<<dim3(512, KK), 256, 0, stream>>>(zin, w1f, statsL);
        k_gemm2f<<<256, 512, 0, stream>>>(zin, w1f, w2f, g1 + l*D2, be1 + l*D2,
                                          params, statsL, hnb);
        if (l < LL-1) k_bnapply_mid<<<6250, 256, 0, stream>>>(hnb, statsL,
                                                              bng + l*DD, bnb + l*DD, hb);
        else          k_bnapply_fin<<<6250, 256, 0, stream>>>(hnb, statsL,
                                                              bng + l*DD, bnb + l*DD,
                                                              (float*)d_out);
    }
}

// Round 14
// 688.900 us; speedup vs baseline: 1.2621x; 1.0498x over previous
//
#include <hip/hip_runtime.h>

// Problem constants (match reference setup_inputs)
#define NV     100000   // nodes
#define DD     128      // hidden dim
#define D2     256      // 2*D
#define EE     600000   // edges per relation
#define KK     3        // relations
#define LL     3        // layers
#define NFEAT  9
#define VOCABS 100

#define NBKT   196      // CSR buckets per relation (512 nodes each)
#define BCAP   8192     // bucket capacity (mean 3061, sigma 55 -> never hit)

typedef __attribute__((ext_vector_type(8))) short short8;
typedef __attribute__((ext_vector_type(4))) float f32x4;
typedef __attribute__((ext_vector_type(2))) float f32x2;
typedef __attribute__((ext_vector_type(4))) unsigned int uint4v;

// params layout (float offsets)
#define PA      0                      // a[3] = softmax(alpha[l])

// per-layer stats region (float offsets within stats + l*2048):
//   ZS(k)=k*512 zsum[256]; ZQ(k)=k*512+256 zsq[256]; HSUM=1536; HSQ=1664
#define ZS(k)  ((k)*512)
#define ZQ(k)  ((k)*512 + 256)
#define HSUM   1536
#define HSQ    1664

// workspace byte offsets (hb padded by 8 zero rows -> zero-row gather trick)
#define HB_OFF   ((size_t)0)            // h (bf16)     (N+8)*128
#define ZIN_OFF  ((size_t)25700000)     // zin_k (bf16, FRAGMENT-TILED) 3 x N*128
#define HNB_OFF  ((size_t)102500000)    // h_next (bf16) N*128
#define O_BASE   ((size_t)128100000)

// zin fragment-tiled layout: granule (16B, 8 elems) of node n, slice (kt,g)
// lives at byte offset  k*NV*256 + (n>>4)*4096 + (kt*4+g)*256 + (n&15)*16.
// Consumers (stats3/gemm2f) load af[k][kt] at base + kt*1024 + lane*16:
// one fully-coalesced 1KB segment per wave (was 16 scattered rows).

__device__ __forceinline__ unsigned short f2bf(float f) {
    union { float f; unsigned int u; } v; v.f = f;
    return (unsigned short)((v.u + 0x7FFFu + ((v.u >> 16) & 1u)) >> 16);
}
__device__ __forceinline__ float bf2f(unsigned short u) {
    union { unsigned int u; float f; } v; v.u = ((unsigned int)u) << 16;
    return v.f;
}
// unpack a bf16 pair (one u32) to f32x2 {lo, hi}
__device__ __forceinline__ f32x2 up2(unsigned int v) {
    union { unsigned int u[2]; f32x2 f; } w;
    w.u[0] = v << 16;
    w.u[1] = v & 0xFFFF0000u;
    return w.f;
}

// h[n,d] = sum_f emb[f, x[n,f], d] -> bf16 ; rows NV..NV+7 zeroed (gather dummy)
__global__ void k_embed(const int* __restrict__ x, const float* __restrict__ emb,
                        unsigned short* __restrict__ hb) {
    int id = blockIdx.x*256 + threadIdx.x;
    int n = id >> 5, q = id & 31;
    if (n >= NV) {
        if (n < NV + 8) *(unsigned long long*)(hb + (size_t)n*DD + q*4) = 0ull;
        return;
    }
    const int* xr = x + n*NFEAT;
    f32x4 acc = {0.f,0.f,0.f,0.f};
    #pragma unroll
    for (int f = 0; f < NFEAT; ++f) {
        int idx = xr[f];
        acc += *(const f32x4*)(emb + ((size_t)(f*VOCABS + idx)*DD + q*4));
    }
    unsigned short pk[4];
    pk[0] = f2bf(acc[0]); pk[1] = f2bf(acc[1]); pk[2] = f2bf(acc[2]); pk[3] = f2bf(acc[3]);
    *(unsigned long long*)(hb + (size_t)n*DD + q*4) = *(unsigned long long*)pk;
}

// ---- CSR build: radix-binned, write-amplification-free ----
__global__ void kA_bin(const int* __restrict__ ke, int* __restrict__ cursor,
                       uint2* __restrict__ pairs) {
    __shared__ int hist[NBKT], excl[NBKT], ofs[NBKT], gbase[NBKT];
    __shared__ int sc[256];
    __shared__ uint2 buf[4096];
    const int rel = blockIdx.y, t = threadIdx.x;
    const int e0 = blockIdx.x * 4096;
    const int cnt = min(4096, EE - e0);
    const int* srcA = ke + (size_t)(rel*2)*EE + e0;
    const int* dstA = ke + (size_t)(rel*2+1)*EE + e0;
    if (t < NBKT) hist[t] = 0;
    __syncthreads();
    for (int i = t; i < cnt; i += 256) atomicAdd(&hist[dstA[i] >> 9], 1);
    __syncthreads();
    const int hv = (t < NBKT) ? hist[t] : 0;
    sc[t] = hv;
    for (int off = 1; off < 256; off <<= 1) {
        __syncthreads();
        int v = (t >= off) ? sc[t-off] : 0;
        __syncthreads();
        sc[t] += v;
    }
    __syncthreads();
    if (t < NBKT) {
        excl[t] = sc[t] - hv;
        ofs[t]  = sc[t] - hv;
        if (hv > 0) gbase[t] = atomicAdd(&cursor[rel*NBKT + t], hv);
    }
    __syncthreads();
    for (int i = t; i < cnt; i += 256) {
        unsigned int s = (unsigned int)srcA[i], d = (unsigned int)dstA[i];
        int p = atomicAdd(&ofs[d >> 9], 1);
        uint2 u; u.x = s; u.y = d;
        buf[p] = u;
    }
    __syncthreads();
    for (int i = t; i < cnt; i += 256) {
        uint2 u = buf[i];
        int b = (int)(u.y >> 9);
        int pos = gbase[b] + (i - excl[b]);
        if (pos < BCAP) pairs[(size_t)(rel*NBKT + b)*BCAP + pos] = u;
    }
}

__global__ void kB_scan(const int* __restrict__ cursor, int* __restrict__ ebase) {
    __shared__ int sc[256];
    const int t = threadIdx.x;
    for (int rel = 0; rel < KK; ++rel) {
        int hv = (t < NBKT) ? min(cursor[rel*NBKT + t], BCAP) : 0;
        sc[t] = hv;
        for (int off = 1; off < 256; off <<= 1) {
            __syncthreads();
            int v = (t >= off) ? sc[t-off] : 0;
            __syncthreads();
            sc[t] += v;
        }
        __syncthreads();
        if (t < NBKT) ebase[rel*NBKT + t] = sc[t] - hv;
        __syncthreads();
    }
}

__global__ void kB_fill(const uint2* __restrict__ pairs, const int* __restrict__ cursor,
                        const int* __restrict__ ebase, int* __restrict__ rp,
                        int* __restrict__ col) {
    __shared__ int h2[512], excl[512], cur[512], sc[256];
    const int b = blockIdx.x, rel = blockIdx.y, t = threadIdx.x;
    const int lo = b * 512;
    const int cnt = min(cursor[rel*NBKT + b], BCAP);
    const int base = ebase[rel*NBKT + b];
    const uint2* P = pairs + (size_t)(rel*NBKT + b)*BCAP;
    h2[t] = 0; h2[t+256] = 0; cur[t] = 0; cur[t+256] = 0;
    __syncthreads();
    for (int i = t; i < cnt; i += 256) atomicAdd(&h2[(int)P[i].y - lo], 1);
    __syncthreads();
    const int a0 = h2[2*t], a1 = h2[2*t+1];
    sc[t] = a0 + a1;
    for (int off = 1; off < 256; off <<= 1) {
        __syncthreads();
        int v = (t >= off) ? sc[t-off] : 0;
        __syncthreads();
        sc[t] += v;
    }
    __syncthreads();
    const int e2 = sc[t] - (a0 + a1);
    excl[2*t] = e2; excl[2*t+1] = e2 + a0;
    __syncthreads();
    for (int tt = t; tt < 512; tt += 256) {
        int n = lo + tt;
        if (n <= NV) rp[(size_t)rel*(NV+1) + n] = base + excl[tt];
    }
    for (int i = t; i < cnt; i += 256) {
        uint2 u = P[i];
        int r = (int)u.y - lo;
        int p = atomicAdd(&cur[r], 1);
        col[(size_t)rel*EE + base + excl[r] + p] = (int)u.x;
    }
}

// Per layer: pack W1/W2 to bf16 MFMA fragments; compute softmax(alpha[l])
__global__ void k_prep(const float* __restrict__ W1, const float* __restrict__ W2,
                       const float* __restrict__ alpha, const int l,
                       unsigned short* __restrict__ w1f, unsigned short* __restrict__ w2f,
                       float* __restrict__ params) {
    int id = blockIdx.x*256 + threadIdx.x;
    if (id == 0) {
        float a0 = alpha[l*KK+0], a1 = alpha[l*KK+1], a2 = alpha[l*KK+2];
        float m = fmaxf(a0, fmaxf(a1, a2));
        float e0 = expf(a0-m), e1 = expf(a1-m), e2 = expf(a2-m);
        float inv = 1.f/(e0+e1+e2);
        params[PA+0] = e0*inv; params[PA+1] = e1*inv; params[PA+2] = e2*inv;
    }
    if (id < 4096) {                       // W1: [128][256]
        int kt = id >> 10, nt = (id >> 6) & 15, lane = id & 63;
        int r = lane & 15, g = lane >> 4;
        const float* Wl = W1 + (size_t)l*DD*D2;
        #pragma unroll
        for (int e = 0; e < 8; ++e) {
            int kk = kt*32 + g*8 + e, c = nt*16 + r;
            w1f[(size_t)id*8 + e] = f2bf(Wl[(size_t)kk*D2 + c]);
        }
    } else if (id < 8192) {                // W2: [256][128]
        int id2 = id - 4096;
        int kt = id2 >> 9, nt = (id2 >> 6) & 7, lane = id2 & 63;
        int r = lane & 15, g = lane >> 4;
        const float* Wl = W2 + (size_t)l*D2*DD;
        #pragma unroll
        for (int e = 0; e < 8; ++e) {
            int kk = kt*32 + g*8 + e, c = nt*16 + r;
            w2f[(size_t)id2*8 + e] = f2bf(Wl[(size_t)kk*DD + c]);
        }
    }
}

// zin_k[n,:] = bf16( (1+eps)*h[n,:] + sum_{j->n,k} h[j,:] )  for all 3 relations.
// One wave per node (n wave-uniform -> SGPR); writes FRAGMENT-TILED zin.
__global__ void k_gather3(const unsigned short* __restrict__ hb, const int* __restrict__ rp,
                          const int* __restrict__ col, const float* __restrict__ epsp,
                          unsigned short* __restrict__ zin) {
    int gid = blockIdx.x*256 + threadIdx.x;
    int n0 = gid >> 6;
    if (n0 >= NV) return;
    const int n = __builtin_amdgcn_readfirstlane(n0);   // wave-uniform -> SGPR
    const int lane = threadIdx.x & 63;
    const int q = lane >> 4, r = lane & 15;
    const int r16 = r << 4;
    const char* hbase = (const char*)hb;
    const float epsv = 1.0f + epsp[0];
    const uint4v sv = *(const uint4v*)(hbase + (((unsigned)n << 8) + r16));
    int b0[KK], dg[KK], cv[KK];
    #pragma unroll
    for (int k = 0; k < KK; ++k) {
        int a = rp[k*(NV+1) + n];
        int b = rp[k*(NV+1) + n + 1];
        b0[k] = a; dg[k] = b - a;
        cv[k] = (lane < dg[k]) ? col[(size_t)k*EE + a + lane] : NV;  // NV = zero row
    }
    f32x2 acc[KK][4];
    #pragma unroll
    for (int k = 0; k < KK; ++k)
        #pragma unroll
        for (int c = 0; c < 4; ++c) acc[k][c] = (f32x2){0.f, 0.f};
    #pragma unroll
    for (int k = 0; k < KK; ++k) {
        const int dc = min(dg[k], 64);            // wave-uniform bound
        for (int base = 0; base < dc; base += 8) {
            int s0 = __shfl(cv[k], base + q);      // lanes all active; idx <= 63
            int s1 = __shfl(cv[k], base + q + 4);
            uint4v v0 = *(const uint4v*)(hbase + (((unsigned)s0 << 8) + r16));
            uint4v v1 = *(const uint4v*)(hbase + (((unsigned)s1 << 8) + r16));
            #pragma unroll
            for (int c = 0; c < 4; ++c) {
                acc[k][c] += up2(v0[c]);
                acc[k][c] += up2(v1[c]);
            }
        }
        // deg > 64 tail: direct col loads (no cross-lane ops)
        for (int j = b0[k] + 64 + q; j < b0[k] + dg[k]; j += 4) {
            int s0 = col[(size_t)k*EE + j];
            uint4v v0 = *(const uint4v*)(hbase + (((unsigned)s0 << 8) + r16));
            #pragma unroll
            for (int c = 0; c < 4; ++c) acc[k][c] += up2(v0[c]);
        }
    }
    #pragma unroll
    for (int k = 0; k < KK; ++k) {
        #pragma unroll
        for (int c = 0; c < 4; ++c) {
            acc[k][c][0] += __shfl_xor(acc[k][c][0], 16);
            acc[k][c][1] += __shfl_xor(acc[k][c][1], 16);
            acc[k][c][0] += __shfl_xor(acc[k][c][0], 32);
            acc[k][c][1] += __shfl_xor(acc[k][c][1], 32);
        }
    }
    if (q == 0) {
        // fragment-tiled store: granule r of node n ->
        //   k*NV*256 + (n>>4)*4096 + r*256 + (n&15)*16
        const unsigned dsto = (((unsigned)n >> 4) << 12) + ((unsigned)r << 8)
                            + (((unsigned)n & 15u) << 4);
        #pragma unroll
        for (int k = 0; k < KK; ++k) {
            uint4v pk;
            #pragma unroll
            for (int c = 0; c < 4; ++c) {
                f32x2 s2 = up2(sv[c]);
                float lo = acc[k][c][0] + epsv * s2[0];
                float hi = acc[k][c][1] + epsv * s2[1];
                unsigned int pko;
                asm("v_cvt_pk_bf16_f32 %0, %1, %2" : "=v"(pko) : "v"(lo), "v"(hi));
                pk[c] = pko;
            }
            *(uint4v*)((char*)zin + (size_t)k*NV*256 + dsto) = pk;
        }
    }
}

// BN1 stats of z1_k = zin_k @ W1 for all relations (grid.y = k), z1 never stored.
// af loads are 1KB coalesced thanks to the fragment-tiled zin layout.
__launch_bounds__(256, 2)
__global__ void k_stats3(const unsigned short* __restrict__ zin,
                         const unsigned short* __restrict__ w1f,
                         float* __restrict__ statsL) {
    __shared__ __align__(16) unsigned short bfr1[32768];  // 64KB W1 frags
    __shared__ float scf[1024];
    const int t = threadIdx.x;
    const int krel = blockIdx.y;
    const char* zk = (const char*)zin + (size_t)krel*NV*256;
    float* zsum = statsL + ZS(krel);
    float* zsq  = statsL + ZQ(krel);
    for (int i = t; i < 4096; i += 256)
        *(uint4v*)(bfr1 + i*8) = *(const uint4v*)(w1f + i*8);
    const int lane = t & 63, w = t >> 6;
    const int r_ = lane & 15, g = lane >> 4;
    const int rt = w & 1, ch = w >> 1;
    __syncthreads();
    float ssum[8] = {0,0,0,0,0,0,0,0};
    float ssq[8]  = {0,0,0,0,0,0,0,0};
    for (int tile = blockIdx.x; tile < NV/32; tile += gridDim.x) {
        short8 af[4];
        #pragma unroll
        for (int kt = 0; kt < 4; ++kt)
            af[kt] = *(const short8*)(zk + (size_t)(tile*2 + rt)*4096 + kt*1024 + lane*16);
        #pragma unroll
        for (int ct = 0; ct < 8; ++ct) {
            const int ntg = ch*8 + ct;
            f32x4 c = {0.f,0.f,0.f,0.f};
            #pragma unroll
            for (int kt = 0; kt < 4; ++kt) {
                short8 b = *(const short8*)(bfr1 + ((size_t)((kt*16 + ntg)*64 + lane))*8);
                c = __builtin_amdgcn_mfma_f32_16x16x32_bf16(af[kt], b, c, 0, 0, 0);
            }
            float s = c[0]+c[1]+c[2]+c[3];
            float q = c[0]*c[0]+c[1]*c[1]+c[2]*c[2]+c[3]*c[3];
            s += __shfl_xor(s, 16); q += __shfl_xor(q, 16);
            s += __shfl_xor(s, 32); q += __shfl_xor(q, 32);
            ssum[ct] += s; ssq[ct] += q;
        }
    }
    if (g == 0) {
        #pragma unroll
        for (int ct = 0; ct < 8; ++ct) {
            const int colc = (ch*8 + ct)*16 + r_;
            scf[rt*256 + colc]       = ssum[ct];
            scf[512 + rt*256 + colc] = ssq[ct];
        }
    }
    __syncthreads();
    atomicAdd(zsum + t, scf[t]       + scf[256 + t]);
    atomicAdd(zsq  + t, scf[512 + t] + scf[768 + t]);
}

// hn = [ sum_k relu(A''_k (zin_k @ W1) + B''_k) ] @ W2 + hn column stats.
// R5-proven structure (8 waves, W1+W2 LDS 128KB, single 16KB yt); af loads
// now 1KB coalesced via the fragment-tiled zin layout. BN1 affine inline.
__launch_bounds__(512, 2)
__global__ void k_gemm2f(const unsigned short* __restrict__ zin,
                         const unsigned short* __restrict__ w1f,
                         const unsigned short* __restrict__ w2f,
                         const float* __restrict__ g1l, const float* __restrict__ be1l,
                         const float* __restrict__ params,
                         float* __restrict__ statsL,
                         unsigned short* __restrict__ hnb) {
    __shared__ __align__(16) unsigned short bfr1[32768];  // 64KB W1 frags
    __shared__ __align__(16) unsigned short bfr2[32768];  // 64KB W2 frags
    __shared__ __align__(16) unsigned char yt[16384];     // 32 x 256 bf16, swizzled
    const int t = threadIdx.x;
    for (int i = t; i < 4096; i += 512)
        *(uint4v*)(bfr1 + i*8) = *(const uint4v*)(w1f + i*8);
    for (int i = t; i < 4096; i += 512)
        *(uint4v*)(bfr2 + i*8) = *(const uint4v*)(w2f + i*8);
    const int lane = t & 63, w = t >> 6;          // 8 waves
    const int r_ = lane & 15, g = lane >> 4;
    const int rt = w & 1, ch = w >> 1;            // rt: row half, ch: col quarter
    const int arow = rt*16 + r_;
    // BN1 affine (a_k folded) computed inline from raw column stats
    float pa1[KK][4], pb1[KK][4];
    #pragma unroll
    for (int k = 0; k < KK; ++k) {
        const float ak = params[PA + k];
        #pragma unroll
        for (int ct = 0; ct < 4; ++ct) {
            const int colc = (ch*4 + ct)*16 + r_;
            float mu  = statsL[ZS(k) + colc] * (1.0f/NV);
            float var = statsL[ZQ(k) + colc] * (1.0f/NV) - mu*mu;
            float A = g1l[colc] * rsqrtf(var + 1e-5f);
            pa1[k][ct] = ak * A;
            pb1[k][ct] = ak * (be1l[colc] - mu*A);
        }
    }
    __syncthreads();
    float ssum[2] = {0,0}, ssq[2] = {0,0};
    for (int tile = blockIdx.x; tile < NV/32; tile += gridDim.x) {
        const int row0 = tile*32;
        // phase 1: y = sum_k relu(BN1_k(zin_k @ W1)); af coalesced 1KB loads
        f32x4 y[4];
        #pragma unroll
        for (int ct = 0; ct < 4; ++ct) y[ct] = (f32x4){0.f,0.f,0.f,0.f};
        short8 af[KK][4];
        #pragma unroll
        for (int k = 0; k < KK; ++k) {
            #pragma unroll
            for (int kt = 0; kt < 4; ++kt)
                af[k][kt] = *(const short8*)((const char*)zin + (size_t)k*NV*256
                              + (size_t)(tile*2 + rt)*4096 + kt*1024 + lane*16);
        }
        #pragma unroll
        for (int k = 0; k < KK; ++k) {
            #pragma unroll
            for (int ct = 0; ct < 4; ++ct) {
                const int ntg = ch*4 + ct;
                f32x4 c = {0.f,0.f,0.f,0.f};
                #pragma unroll
                for (int kt = 0; kt < 4; ++kt) {
                    short8 b = *(const short8*)(bfr1 + ((size_t)((kt*16 + ntg)*64 + lane))*8);
                    c = __builtin_amdgcn_mfma_f32_16x16x32_bf16(af[k][kt], b, c, 0, 0, 0);
                }
                #pragma unroll
                for (int reg = 0; reg < 4; ++reg)
                    y[ct][reg] += fmaxf(pa1[k][ct]*c[reg] + pb1[k][ct], 0.0f);
            }
        }
        __syncthreads();   // prev phase2 done reading yt
        #pragma unroll
        for (int ct = 0; ct < 4; ++ct) {
            const int col2 = ((ch*4 + ct)*16 + r_)*2;
            #pragma unroll
            for (int reg = 0; reg < 4; ++reg) {
                const int row = rt*16 + g*4 + reg;
                *(unsigned short*)(yt + row*512 + (col2 ^ ((row & 15) << 4))) = f2bf(y[ct][reg]);
            }
        }
        __syncthreads();
        // phase 2: hn = y @ W2 (W2 from LDS)
        short8 ya[8];
        #pragma unroll
        for (int kt = 0; kt < 8; ++kt)
            ya[kt] = *(const short8*)(yt + arow*512 + ((kt*64 + g*16) ^ ((arow & 15) << 4)));
        #pragma unroll
        for (int ct2 = 0; ct2 < 2; ++ct2) {
            const int ntg2 = ch*2 + ct2;
            f32x4 c = {0.f,0.f,0.f,0.f};
            #pragma unroll
            for (int kt = 0; kt < 8; ++kt) {
                short8 b = *(const short8*)(bfr2 + ((size_t)((kt*8 + ntg2)*64 + lane))*8);
                c = __builtin_amdgcn_mfma_f32_16x16x32_bf16(ya[kt], b, c, 0, 0, 0);
            }
            unsigned short* hp = hnb + (size_t)(row0 + rt*16 + g*4)*DD + ntg2*16 + r_;
            float ps = 0.0f, pq = 0.0f;
            #pragma unroll
            for (int reg = 0; reg < 4; ++reg) {
                float xv = c[reg];
                hp[(size_t)reg*DD] = f2bf(xv);
                ps += xv; pq += xv*xv;
            }
            ps += __shfl_xor(ps, 16); pq += __shfl_xor(pq, 16);
            ps += __shfl_xor(ps, 32); pq += __shfl_xor(pq, 32);
            ssum[ct2] += ps; ssq[ct2] += pq;
        }
    }
    // flush hn column stats (reuse yt; wave w covers cols ch*32 .. ch*32+31)
    __syncthreads();
    float* scf = (float*)yt;
    if (g == 0) {
        #pragma unroll
        for (int ct2 = 0; ct2 < 2; ++ct2) {
            scf[w*32 + ct2*16 + r_]       = ssum[ct2];
            scf[256 + w*32 + ct2*16 + r_] = ssq[ct2];
        }
    }
    __syncthreads();
    if (t < 128) {
        const int chc = t >> 5, idx = t & 31;
        float s = 0.0f, q = 0.0f;
        #pragma unroll
        for (int rr = 0; rr < 2; ++rr) {
            s += scf[(chc*2 + rr)*32 + idx];
            q += scf[256 + (chc*2 + rr)*32 + idx];
        }
        atomicAdd(statsL + HSUM + t, s);
        atomicAdd(statsL + HSQ + t, q);
    }
}

// mid layers: h(bf16) = relu(BN2(hn)); BN2 affine computed inline from stats
__global__ void k_bnapply_mid(const unsigned short* __restrict__ hnb,
                              const float* __restrict__ statsL,
                              const float* __restrict__ bng, const float* __restrict__ bnb,
                              unsigned short* __restrict__ hb) {
    int id = blockIdx.x*256 + threadIdx.x;       // 6250 blocks * 8 elems
    const int col0 = (id & 15)*8;
    short8 v = *(const short8*)(hnb + (size_t)id*8);
    short8 o;
    #pragma unroll
    for (int j = 0; j < 8; ++j) {
        const int c = col0 + j;
        float mu  = statsL[HSUM + c] * (1.0f/NV);
        float var = statsL[HSQ + c] * (1.0f/NV) - mu*mu;
        float A = bng[c] * rsqrtf(var + 1e-5f);
        float B = bnb[c] - mu*A;
        o[j] = (short)f2bf(fmaxf(A*bf2f((unsigned short)v[j]) + B, 0.0f));
    }
    *(short8*)(hb + (size_t)id*8) = o;
}

// final layer: d_out(f32) = relu(BN2(hn))
__global__ void k_bnapply_fin(const unsigned short* __restrict__ hnb,
                              const float* __restrict__ statsL,
                              const float* __restrict__ bng, const float* __restrict__ bnb,
                              float* __restrict__ out) {
    int id = blockIdx.x*256 + threadIdx.x;
    const int col0 = (id & 15)*8;
    short8 v = *(const short8*)(hnb + (size_t)id*8);
    f32x4 o0, o1;
    #pragma unroll
    for (int j = 0; j < 8; ++j) {
        const int c = col0 + j;
        float mu  = statsL[HSUM + c] * (1.0f/NV);
        float var = statsL[HSQ + c] * (1.0f/NV) - mu*mu;
        float A = bng[c] * rsqrtf(var + 1e-5f);
        float B = bnb[c] - mu*A;
        float r = fmaxf(A*bf2f((unsigned short)v[j]) + B, 0.0f);
        if (j < 4) o0[j] = r; else o1[j-4] = r;
    }
    *(f32x4*)(out + (size_t)id*8)     = o0;
    *(f32x4*)(out + (size_t)id*8 + 4) = o1;
}

extern "C" void kernel_launch(void* const* d_in, const int* in_sizes, int n_in,
                              void* d_out, int out_size, void* d_ws, size_t ws_size,
                              hipStream_t stream) {
    const int*   x     = (const int*)d_in[0];
    const int*   ke    = (const int*)d_in[1];
    const float* emb   = (const float*)d_in[2];
    const float* W1    = (const float*)d_in[3];
    // d_in[4] = b1: per-column shift cancels exactly through training-mode BN
    const float* g1    = (const float*)d_in[5];
    const float* be1   = (const float*)d_in[6];
    const float* W2    = (const float*)d_in[7];
    // d_in[8] = b2: cancels through final BN (softmax weights sum to 1)
    const float* eps   = (const float*)d_in[9];
    const float* alpha = (const float*)d_in[10];
    const float* bng   = (const float*)d_in[11];
    const float* bnb   = (const float*)d_in[12];

    char* ws = (char*)d_ws;
    unsigned short* hb     = (unsigned short*)(ws + HB_OFF);
    unsigned short* zin    = (unsigned short*)(ws + ZIN_OFF);   // 3 buffers, tiled
    unsigned short* hnb    = (unsigned short*)(ws + HNB_OFF);
    size_t o = O_BASE;
    unsigned short* w1f    = (unsigned short*)(ws + o);          o += 65536;
    unsigned short* w2f    = (unsigned short*)(ws + o);          o += 65536;
    float*          stats  = (float*)(ws + o);                   o += 32768;  // 3 x 2048 floats
    float*          params = (float*)(ws + o);                   o += 4096;
    int*            rp     = (int*)(ws + o);                     o += 1200128;
    int*            col    = (int*)(ws + o);                     o += 7200000;
    int*            cur    = (int*)(ws + o);                     o += 4096;
    int*            ebase  = (int*)(ws + o);                     o += 4096;
    uint2*          pairs  = (uint2*)(ws + ZIN_OFF);             // aliased (pre-zin)

    // AtomEncoder (+ zero-pad rows NV..NV+7 for the gather dummy row)
    k_embed<<<12501, 256, 0, stream>>>(x, emb, hb);

    // CSR build (shared by all layers; uses pairs alias before any zin write)
    hipMemsetAsync(cur, 0, KK*NBKT*sizeof(int), stream);
    hipMemsetAsync(stats, 0, 3*2048*sizeof(float), stream);   // all layers' stats
    kA_bin<<<dim3(147, KK), 256, 0, stream>>>(ke, cur, pairs);
    kB_scan<<<1, 256, 0, stream>>>(cur, ebase);
    kB_fill<<<dim3(NBKT, KK), 256, 0, stream>>>(pairs, cur, ebase, rp, col);

    for (int l = 0; l < LL; ++l) {
        float* statsL = stats + (size_t)l*2048;
        k_prep<<<32, 256, 0, stream>>>(W1, W2, alpha, l, w1f, w2f, params);
        k_gather3<<<25000, 256, 0, stream>>>(hb, rp, col, eps + l, zin);
        k_stats3<<<dim3(512, KK), 256, 0, stream>>>(zin, w1f, statsL);
        k_gemm2f<<<256, 512, 0, stream>>>(zin, w1f, w2f, g1 + l*D2, be1 + l*D2,
                                          params, statsL, hnb);
        if (l < LL-1) k_bnapply_mid<<<6250, 256, 0, stream>>>(hnb, statsL,
                                                              bng + l*DD, bnb + l*DD, hb);
        else          k_bnapply_fin<<<6250, 256, 0, stream>>>(hnb, statsL,
                                                              bng + l*DD, bnb + l*DD,
                                                              (float*)d_out);
    }
}

// Round 15
// 653.688 us; speedup vs baseline: 1.3301x; 1.0539x over previous
//
#include <hip/hip_runtime.h>

// Problem constants (match reference setup_inputs)
#define NV     100000   // nodes
#define DD     128      // hidden dim
#define D2     256      // 2*D
#define EE     600000   // edges per relation
#define KK     3        // relations
#define LL     3        // layers
#define NFEAT  9
#define VOCABS 100

#define NBKT   196      // CSR buckets per relation (512 nodes each)
#define BCAP   8192     // bucket capacity (mean 3061, sigma 55 -> never hit)

typedef __attribute__((ext_vector_type(8))) short short8;
typedef __attribute__((ext_vector_type(4))) float f32x4;
typedef __attribute__((ext_vector_type(2))) float f32x2;
typedef __attribute__((ext_vector_type(4))) unsigned int uint4v;

// params: per layer l, params[l*4 + k] = softmax(alpha[l])[k]
// per-layer stats region (float offsets within stats + l*2048):
#define ZS(k)  ((k)*512)
#define ZQ(k)  ((k)*512 + 256)
#define HSUM   1536
#define HSQ    1664

// workspace byte offsets (hb padded by 8 zero rows -> zero-row gather trick)
#define HB_OFF   ((size_t)0)            // h (bf16)     (N+8)*128
#define ZIN_OFF  ((size_t)25700000)     // zin_k (bf16, FRAGMENT-TILED) 3 x N*128
#define HNB_OFF  ((size_t)102500000)    // h_next (bf16) N*128
#define O_BASE   ((size_t)128100000)

// zin fragment-tiled layout: granule (16B, 8 elems) of node n, slice (kt,g)
// lives at byte offset  k*NV*256 + (n>>4)*4096 + (kt*4+g)*256 + (n&15)*16.
// Consumers (stats3/gemm2f) load af[k][kt] at base + kt*1024 + lane*16:
// one fully-coalesced 1KB segment per wave.

__device__ __forceinline__ unsigned short f2bf(float f) {
    union { float f; unsigned int u; } v; v.f = f;
    return (unsigned short)((v.u + 0x7FFFu + ((v.u >> 16) & 1u)) >> 16);
}
__device__ __forceinline__ float bf2f(unsigned short u) {
    union { unsigned int u; float f; } v; v.u = ((unsigned int)u) << 16;
    return v.f;
}
// unpack a bf16 pair (one u32) to f32x2 {lo, hi}
__device__ __forceinline__ f32x2 up2(unsigned int v) {
    union { unsigned int u[2]; f32x2 f; } w;
    w.u[0] = v << 16;
    w.u[1] = v & 0xFFFF0000u;
    return w.f;
}

// h[n,d] = sum_f emb[f, x[n,f], d] -> bf16 ; rows NV..NV+7 zeroed (gather dummy)
__global__ void k_embed(const int* __restrict__ x, const float* __restrict__ emb,
                        unsigned short* __restrict__ hb) {
    int id = blockIdx.x*256 + threadIdx.x;
    int n = id >> 5, q = id & 31;
    if (n >= NV) {
        if (n < NV + 8) *(unsigned long long*)(hb + (size_t)n*DD + q*4) = 0ull;
        return;
    }
    const int* xr = x + n*NFEAT;
    f32x4 acc = {0.f,0.f,0.f,0.f};
    #pragma unroll
    for (int f = 0; f < NFEAT; ++f) {
        int idx = xr[f];
        acc += *(const f32x4*)(emb + ((size_t)(f*VOCABS + idx)*DD + q*4));
    }
    unsigned short pk[4];
    pk[0] = f2bf(acc[0]); pk[1] = f2bf(acc[1]); pk[2] = f2bf(acc[2]); pk[3] = f2bf(acc[3]);
    *(unsigned long long*)(hb + (size_t)n*DD + q*4) = *(unsigned long long*)pk;
}

// ---- CSR build: radix-binned; pairs packed to u32 (dstloc[9]<<17 | src[17]) ----
__global__ void kA_bin(const int* __restrict__ ke, int* __restrict__ cursor,
                       unsigned int* __restrict__ pairs) {
    __shared__ int hist[NBKT], excl[NBKT], ofs[NBKT], gbase[NBKT];
    __shared__ int sc[256];
    __shared__ unsigned int buf[4096];
    const int rel = blockIdx.y, t = threadIdx.x;
    const int e0 = blockIdx.x * 4096;
    const int cnt = min(4096, EE - e0);
    const int* srcA = ke + (size_t)(rel*2)*EE + e0;
    const int* dstA = ke + (size_t)(rel*2+1)*EE + e0;
    if (t < NBKT) hist[t] = 0;
    __syncthreads();
    for (int i = t; i < cnt; i += 256) atomicAdd(&hist[dstA[i] >> 9], 1);
    __syncthreads();
    const int hv = (t < NBKT) ? hist[t] : 0;
    sc[t] = hv;
    for (int off = 1; off < 256; off <<= 1) {
        __syncthreads();
        int v = (t >= off) ? sc[t-off] : 0;
        __syncthreads();
        sc[t] += v;
    }
    __syncthreads();
    if (t < NBKT) {
        excl[t] = sc[t] - hv;
        ofs[t]  = sc[t] - hv;
        if (hv > 0) gbase[t] = atomicAdd(&cursor[rel*NBKT + t], hv);
    }
    __syncthreads();
    for (int i = t; i < cnt; i += 256) {
        unsigned int s = (unsigned int)srcA[i], d = (unsigned int)dstA[i];
        int p = atomicAdd(&ofs[d >> 9], 1);
        buf[p] = ((d & 511u) << 17) | s;
    }
    __syncthreads();
    for (int i = t; i < cnt; i += 256) {
        unsigned int u = buf[i];
        // bucket id must come from dst; recover via ofs-partition: we stored by
        // bucket order, so find bucket by position: use excl[] boundaries is
        // costly -- instead recompute from the original stream is not possible.
        // Simplest: store bucket in bits too? 26 bits used; bucket = 8 bits of
        // (dst>>9) < 196 fits in remaining 6? No (needs 8). Use second array:
        // Instead recompute d from partition: NOT available. -> keep a parallel
        // approach: we re-read dstA to get bucket for write-out position i.
        // (positions in buf were permuted; cannot pair with dstA[i].)
        // Fallback: derive bucket by binary search over excl (8 steps, SALU-ish).
        int lo = 0, hi = NBKT - 1;
        #pragma unroll
        for (int s2 = 0; s2 < 8; ++s2) {
            int mid = (lo + hi + 1) >> 1;
            bool ge = (i >= excl[mid]);
            lo = ge ? mid : lo;
            hi = ge ? hi : mid - 1;
        }
        const int b = lo;
        int pos = gbase[b] + (i - excl[b]);
        if (pos < BCAP) pairs[(size_t)(rel*NBKT + b)*BCAP + pos] = u;
    }
}

__global__ void kB_scan(const int* __restrict__ cursor, int* __restrict__ ebase) {
    __shared__ int sc[256];
    const int t = threadIdx.x;
    for (int rel = 0; rel < KK; ++rel) {
        int hv = (t < NBKT) ? min(cursor[rel*NBKT + t], BCAP) : 0;
        sc[t] = hv;
        for (int off = 1; off < 256; off <<= 1) {
            __syncthreads();
            int v = (t >= off) ? sc[t-off] : 0;
            __syncthreads();
            sc[t] += v;
        }
        __syncthreads();
        if (t < NBKT) ebase[rel*NBKT + t] = sc[t] - hv;
        __syncthreads();
    }
}

__global__ void kB_fill(const unsigned int* __restrict__ pairs, const int* __restrict__ cursor,
                        const int* __restrict__ ebase, int* __restrict__ rp,
                        int* __restrict__ col) {
    __shared__ int h2[512], excl[512], cur[512], sc[256];
    const int b = blockIdx.x, rel = blockIdx.y, t = threadIdx.x;
    const int lo = b * 512;
    const int cnt = min(cursor[rel*NBKT + b], BCAP);
    const int base = ebase[rel*NBKT + b];
    const unsigned int* P = pairs + (size_t)(rel*NBKT + b)*BCAP;
    h2[t] = 0; h2[t+256] = 0; cur[t] = 0; cur[t+256] = 0;
    __syncthreads();
    for (int i = t; i < cnt; i += 256) atomicAdd(&h2[P[i] >> 17], 1);
    __syncthreads();
    const int a0 = h2[2*t], a1 = h2[2*t+1];
    sc[t] = a0 + a1;
    for (int off = 1; off < 256; off <<= 1) {
        __syncthreads();
        int v = (t >= off) ? sc[t-off] : 0;
        __syncthreads();
        sc[t] += v;
    }
    __syncthreads();
    const int e2 = sc[t] - (a0 + a1);
    excl[2*t] = e2; excl[2*t+1] = e2 + a0;
    __syncthreads();
    for (int tt = t; tt < 512; tt += 256) {
        int n = lo + tt;
        if (n <= NV) rp[(size_t)rel*(NV+1) + n] = base + excl[tt];
    }
    for (int i = t; i < cnt; i += 256) {
        unsigned int u = P[i];
        int r = (int)(u >> 17);
        int p = atomicAdd(&cur[r], 1);
        col[(size_t)rel*EE + base + excl[r] + p] = (int)(u & 0x1FFFFu);
    }
}

// ALL layers at once: pack W1/W2 to bf16 MFMA fragments; softmax(alpha[l]).
__global__ void k_prep_all(const float* __restrict__ W1, const float* __restrict__ W2,
                           const float* __restrict__ alpha,
                           unsigned short* __restrict__ w1f, unsigned short* __restrict__ w2f,
                           float* __restrict__ params) {
    const int l = blockIdx.y;
    int id = blockIdx.x*256 + threadIdx.x;
    if (id == 0) {
        float a0 = alpha[l*KK+0], a1 = alpha[l*KK+1], a2 = alpha[l*KK+2];
        float m = fmaxf(a0, fmaxf(a1, a2));
        float e0 = expf(a0-m), e1 = expf(a1-m), e2 = expf(a2-m);
        float inv = 1.f/(e0+e1+e2);
        params[l*4+0] = e0*inv; params[l*4+1] = e1*inv; params[l*4+2] = e2*inv;
    }
    if (id < 4096) {                       // W1: [128][256]
        int kt = id >> 10, nt = (id >> 6) & 15, lane = id & 63;
        int r = lane & 15, g = lane >> 4;
        const float* Wl = W1 + (size_t)l*DD*D2;
        #pragma unroll
        for (int e = 0; e < 8; ++e) {
            int kk = kt*32 + g*8 + e, c = nt*16 + r;
            w1f[(size_t)l*32768 + (size_t)id*8 + e] = f2bf(Wl[(size_t)kk*D2 + c]);
        }
    } else if (id < 8192) {                // W2: [256][128]
        int id2 = id - 4096;
        int kt = id2 >> 9, nt = (id2 >> 6) & 7, lane = id2 & 63;
        int r = lane & 15, g = lane >> 4;
        const float* Wl = W2 + (size_t)l*D2*DD;
        #pragma unroll
        for (int e = 0; e < 8; ++e) {
            int kk = kt*32 + g*8 + e, c = nt*16 + r;
            w2f[(size_t)l*32768 + (size_t)id2*8 + e] = f2bf(Wl[(size_t)kk*DD + c]);
        }
    }
}

// zin_k[n,:] = bf16( (1+eps)*h[n,:] + sum_{j->n,k} h[j,:] )  for all 3 relations.
// One wave per node (n wave-uniform -> SGPR); writes FRAGMENT-TILED zin.
__global__ void k_gather3(const unsigned short* __restrict__ hb, const int* __restrict__ rp,
                          const int* __restrict__ col, const float* __restrict__ epsp,
                          unsigned short* __restrict__ zin) {
    int gid = blockIdx.x*256 + threadIdx.x;
    int n0 = gid >> 6;
    if (n0 >= NV) return;
    const int n = __builtin_amdgcn_readfirstlane(n0);   // wave-uniform -> SGPR
    const int lane = threadIdx.x & 63;
    const int q = lane >> 4, r = lane & 15;
    const int r16 = r << 4;
    const char* hbase = (const char*)hb;
    const float epsv = 1.0f + epsp[0];
    const uint4v sv = *(const uint4v*)(hbase + (((unsigned)n << 8) + r16));
    int b0[KK], dg[KK], cv[KK];
    #pragma unroll
    for (int k = 0; k < KK; ++k) {
        int a = rp[k*(NV+1) + n];
        int b = rp[k*(NV+1) + n + 1];
        b0[k] = a; dg[k] = b - a;
        cv[k] = (lane < dg[k]) ? col[(size_t)k*EE + a + lane] : NV;  // NV = zero row
    }
    f32x2 acc[KK][4];
    #pragma unroll
    for (int k = 0; k < KK; ++k)
        #pragma unroll
        for (int c = 0; c < 4; ++c) acc[k][c] = (f32x2){0.f, 0.f};
    #pragma unroll
    for (int k = 0; k < KK; ++k) {
        const int dc = min(dg[k], 64);            // wave-uniform bound
        for (int base = 0; base < dc; base += 8) {
            int s0 = __shfl(cv[k], base + q);      // lanes all active; idx <= 63
            int s1 = __shfl(cv[k], base + q + 4);
            uint4v v0 = *(const uint4v*)(hbase + (((unsigned)s0 << 8) + r16));
            uint4v v1 = *(const uint4v*)(hbase + (((unsigned)s1 << 8) + r16));
            #pragma unroll
            for (int c = 0; c < 4; ++c) {
                acc[k][c] += up2(v0[c]);
                acc[k][c] += up2(v1[c]);
            }
        }
        // deg > 64 tail: direct col loads (no cross-lane ops)
        for (int j = b0[k] + 64 + q; j < b0[k] + dg[k]; j += 4) {
            int s0 = col[(size_t)k*EE + j];
            uint4v v0 = *(const uint4v*)(hbase + (((unsigned)s0 << 8) + r16));
            #pragma unroll
            for (int c = 0; c < 4; ++c) acc[k][c] += up2(v0[c]);
        }
    }
    #pragma unroll
    for (int k = 0; k < KK; ++k) {
        #pragma unroll
        for (int c = 0; c < 4; ++c) {
            acc[k][c][0] += __shfl_xor(acc[k][c][0], 16);
            acc[k][c][1] += __shfl_xor(acc[k][c][1], 16);
            acc[k][c][0] += __shfl_xor(acc[k][c][0], 32);
            acc[k][c][1] += __shfl_xor(acc[k][c][1], 32);
        }
    }
    if (q == 0) {
        // fragment-tiled store: granule r of node n ->
        //   k*NV*256 + (n>>4)*4096 + r*256 + (n&15)*16
        const unsigned dsto = (((unsigned)n >> 4) << 12) + ((unsigned)r << 8)
                            + (((unsigned)n & 15u) << 4);
        #pragma unroll
        for (int k = 0; k < KK; ++k) {
            uint4v pk;
            #pragma unroll
            for (int c = 0; c < 4; ++c) {
                f32x2 s2 = up2(sv[c]);
                float lo = acc[k][c][0] + epsv * s2[0];
                float hi = acc[k][c][1] + epsv * s2[1];
                unsigned int pko;
                asm("v_cvt_pk_bf16_f32 %0, %1, %2" : "=v"(pko) : "v"(lo), "v"(hi));
                pk[c] = pko;
            }
            *(uint4v*)((char*)zin + (size_t)k*NV*256 + dsto) = pk;
        }
    }
}

// BN1 stats of z1_k = zin_k @ W1 for ALL relations (looped inside; W1 staged
// once per block). Grid 256 so staging traffic is 256x64KB, not 1536x64KB.
__launch_bounds__(256, 2)
__global__ void k_stats3(const unsigned short* __restrict__ zin,
                         const unsigned short* __restrict__ w1f,
                         float* __restrict__ statsL) {
    __shared__ __align__(16) unsigned short bfr1[32768];  // 64KB W1 frags
    __shared__ float scf[1024];
    const int t = threadIdx.x;
    for (int i = t; i < 4096; i += 256)
        *(uint4v*)(bfr1 + i*8) = *(const uint4v*)(w1f + i*8);
    const int lane = t & 63, w = t >> 6;
    const int r_ = lane & 15, g = lane >> 4;
    const int rt = w & 1, ch = w >> 1;
    __syncthreads();
    for (int krel = 0; krel < KK; ++krel) {
        const char* zk = (const char*)zin + (size_t)krel*NV*256;
        float ssum[8] = {0,0,0,0,0,0,0,0};
        float ssq[8]  = {0,0,0,0,0,0,0,0};
        for (int tile = blockIdx.x; tile < NV/32; tile += gridDim.x) {
            short8 af[4];
            #pragma unroll
            for (int kt = 0; kt < 4; ++kt)
                af[kt] = *(const short8*)(zk + (size_t)(tile*2 + rt)*4096 + kt*1024 + lane*16);
            #pragma unroll
            for (int ct = 0; ct < 8; ++ct) {
                const int ntg = ch*8 + ct;
                f32x4 c = {0.f,0.f,0.f,0.f};
                #pragma unroll
                for (int kt = 0; kt < 4; ++kt) {
                    short8 b = *(const short8*)(bfr1 + ((size_t)((kt*16 + ntg)*64 + lane))*8);
                    c = __builtin_amdgcn_mfma_f32_16x16x32_bf16(af[kt], b, c, 0, 0, 0);
                }
                float s = c[0]+c[1]+c[2]+c[3];
                float q = c[0]*c[0]+c[1]*c[1]+c[2]*c[2]+c[3]*c[3];
                s += __shfl_xor(s, 16); q += __shfl_xor(q, 16);
                s += __shfl_xor(s, 32); q += __shfl_xor(q, 32);
                ssum[ct] += s; ssq[ct] += q;
            }
        }
        __syncthreads();   // prior krel's atomics done reading scf
        if (g == 0) {
            #pragma unroll
            for (int ct = 0; ct < 8; ++ct) {
                const int colc = (ch*8 + ct)*16 + r_;
                scf[rt*256 + colc]       = ssum[ct];
                scf[512 + rt*256 + colc] = ssq[ct];
            }
        }
        __syncthreads();
        atomicAdd(statsL + ZS(krel) + t, scf[t]       + scf[256 + t]);
        atomicAdd(statsL + ZQ(krel) + t, scf[512 + t] + scf[768 + t]);
    }
}

// hn = [ sum_k relu(A''_k (zin_k @ W1) + B''_k) ] @ W2 + hn column stats.
// R5-proven structure (8 waves, W1+W2 LDS 128KB, single 16KB yt); af loads
// 1KB coalesced via the fragment-tiled zin layout. BN1 affine inline.
__launch_bounds__(512, 2)
__global__ void k_gemm2f(const unsigned short* __restrict__ zin,
                         const unsigned short* __restrict__ w1f,
                         const unsigned short* __restrict__ w2f,
                         const float* __restrict__ g1l, const float* __restrict__ be1l,
                         const float* __restrict__ params,
                         float* __restrict__ statsL,
                         unsigned short* __restrict__ hnb) {
    __shared__ __align__(16) unsigned short bfr1[32768];  // 64KB W1 frags
    __shared__ __align__(16) unsigned short bfr2[32768];  // 64KB W2 frags
    __shared__ __align__(16) unsigned char yt[16384];     // 32 x 256 bf16, swizzled
    const int t = threadIdx.x;
    for (int i = t; i < 4096; i += 512)
        *(uint4v*)(bfr1 + i*8) = *(const uint4v*)(w1f + i*8);
    for (int i = t; i < 4096; i += 512)
        *(uint4v*)(bfr2 + i*8) = *(const uint4v*)(w2f + i*8);
    const int lane = t & 63, w = t >> 6;          // 8 waves
    const int r_ = lane & 15, g = lane >> 4;
    const int rt = w & 1, ch = w >> 1;            // rt: row half, ch: col quarter
    const int arow = rt*16 + r_;
    // BN1 affine (a_k folded) computed inline from raw column stats
    float pa1[KK][4], pb1[KK][4];
    #pragma unroll
    for (int k = 0; k < KK; ++k) {
        const float ak = params[k];
        #pragma unroll
        for (int ct = 0; ct < 4; ++ct) {
            const int colc = (ch*4 + ct)*16 + r_;
            float mu  = statsL[ZS(k) + colc] * (1.0f/NV);
            float var = statsL[ZQ(k) + colc] * (1.0f/NV) - mu*mu;
            float A = g1l[colc] * rsqrtf(var + 1e-5f);
            pa1[k][ct] = ak * A;
            pb1[k][ct] = ak * (be1l[colc] - mu*A);
        }
    }
    __syncthreads();
    float ssum[2] = {0,0}, ssq[2] = {0,0};
    for (int tile = blockIdx.x; tile < NV/32; tile += gridDim.x) {
        const int row0 = tile*32;
        // phase 1: y = sum_k relu(BN1_k(zin_k @ W1)); af coalesced 1KB loads
        f32x4 y[4];
        #pragma unroll
        for (int ct = 0; ct < 4; ++ct) y[ct] = (f32x4){0.f,0.f,0.f,0.f};
        short8 af[KK][4];
        #pragma unroll
        for (int k = 0; k < KK; ++k) {
            #pragma unroll
            for (int kt = 0; kt < 4; ++kt)
                af[k][kt] = *(const short8*)((const char*)zin + (size_t)k*NV*256
                              + (size_t)(tile*2 + rt)*4096 + kt*1024 + lane*16);
        }
        #pragma unroll
        for (int k = 0; k < KK; ++k) {
            #pragma unroll
            for (int ct = 0; ct < 4; ++ct) {
                const int ntg = ch*4 + ct;
                f32x4 c = {0.f,0.f,0.f,0.f};
                #pragma unroll
                for (int kt = 0; kt < 4; ++kt) {
                    short8 b = *(const short8*)(bfr1 + ((size_t)((kt*16 + ntg)*64 + lane))*8);
                    c = __builtin_amdgcn_mfma_f32_16x16x32_bf16(af[k][kt], b, c, 0, 0, 0);
                }
                #pragma unroll
                for (int reg = 0; reg < 4; ++reg)
                    y[ct][reg] += fmaxf(pa1[k][ct]*c[reg] + pb1[k][ct], 0.0f);
            }
        }
        __syncthreads();   // prev phase2 done reading yt
        #pragma unroll
        for (int ct = 0; ct < 4; ++ct) {
            const int col2 = ((ch*4 + ct)*16 + r_)*2;
            #pragma unroll
            for (int reg = 0; reg < 4; ++reg) {
                const int row = rt*16 + g*4 + reg;
                *(unsigned short*)(yt + row*512 + (col2 ^ ((row & 15) << 4))) = f2bf(y[ct][reg]);
            }
        }
        __syncthreads();
        // phase 2: hn = y @ W2 (W2 from LDS)
        short8 ya[8];
        #pragma unroll
        for (int kt = 0; kt < 8; ++kt)
            ya[kt] = *(const short8*)(yt + arow*512 + ((kt*64 + g*16) ^ ((arow & 15) << 4)));
        #pragma unroll
        for (int ct2 = 0; ct2 < 2; ++ct2) {
            const int ntg2 = ch*2 + ct2;
            f32x4 c = {0.f,0.f,0.f,0.f};
            #pragma unroll
            for (int kt = 0; kt < 8; ++kt) {
                short8 b = *(const short8*)(bfr2 + ((size_t)((kt*8 + ntg2)*64 + lane))*8);
                c = __builtin_amdgcn_mfma_f32_16x16x32_bf16(ya[kt], b, c, 0, 0, 0);
            }
            unsigned short* hp = hnb + (size_t)(row0 + rt*16 + g*4)*DD + ntg2*16 + r_;
            float ps = 0.0f, pq = 0.0f;
            #pragma unroll
            for (int reg = 0; reg < 4; ++reg) {
                float xv = c[reg];
                hp[(size_t)reg*DD] = f2bf(xv);
                ps += xv; pq += xv*xv;
            }
            ps += __shfl_xor(ps, 16); pq += __shfl_xor(pq, 16);
            ps += __shfl_xor(ps, 32); pq += __shfl_xor(pq, 32);
            ssum[ct2] += ps; ssq[ct2] += pq;
        }
    }
    // flush hn column stats (reuse yt; wave w covers cols ch*32 .. ch*32+31)
    __syncthreads();
    float* scf = (float*)yt;
    if (g == 0) {
        #pragma unroll
        for (int ct2 = 0; ct2 < 2; ++ct2) {
            scf[w*32 + ct2*16 + r_]       = ssum[ct2];
            scf[256 + w*32 + ct2*16 + r_] = ssq[ct2];
        }
    }
    __syncthreads();
    if (t < 128) {
        const int chc = t >> 5, idx = t & 31;
        float s = 0.0f, q = 0.0f;
        #pragma unroll
        for (int rr = 0; rr < 2; ++rr) {
            s += scf[(chc*2 + rr)*32 + idx];
            q += scf[256 + (chc*2 + rr)*32 + idx];
        }
        atomicAdd(statsL + HSUM + t, s);
        atomicAdd(statsL + HSQ + t, q);
    }
}

// mid layers: h(bf16) = relu(BN2(hn)); BN2 affine computed inline from stats
__global__ void k_bnapply_mid(const unsigned short* __restrict__ hnb,
                              const float* __restrict__ statsL,
                              const float* __restrict__ bng, const float* __restrict__ bnb,
                              unsigned short* __restrict__ hb) {
    int id = blockIdx.x*256 + threadIdx.x;       // 6250 blocks * 8 elems
    const int col0 = (id & 15)*8;
    short8 v = *(const short8*)(hnb + (size_t)id*8);
    short8 o;
    #pragma unroll
    for (int j = 0; j < 8; ++j) {
        const int c = col0 + j;
        float mu  = statsL[HSUM + c] * (1.0f/NV);
        float var = statsL[HSQ + c] * (1.0f/NV) - mu*mu;
        float A = bng[c] * rsqrtf(var + 1e-5f);
        float B = bnb[c] - mu*A;
        o[j] = (short)f2bf(fmaxf(A*bf2f((unsigned short)v[j]) + B, 0.0f));
    }
    *(short8*)(hb + (size_t)id*8) = o;
}

// final layer: d_out(f32) = relu(BN2(hn))
__global__ void k_bnapply_fin(const unsigned short* __restrict__ hnb,
                              const float* __restrict__ statsL,
                              const float* __restrict__ bng, const float* __restrict__ bnb,
                              float* __restrict__ out) {
    int id = blockIdx.x*256 + threadIdx.x;
    const int col0 = (id & 15)*8;
    short8 v = *(const short8*)(hnb + (size_t)id*8);
    f32x4 o0, o1;
    #pragma unroll
    for (int j = 0; j < 8; ++j) {
        const int c = col0 + j;
        float mu  = statsL[HSUM + c] * (1.0f/NV);
        float var = statsL[HSQ + c] * (1.0f/NV) - mu*mu;
        float A = bng[c] * rsqrtf(var + 1e-5f);
        float B = bnb[c] - mu*A;
        float r = fmaxf(A*bf2f((unsigned short)v[j]) + B, 0.0f);
        if (j < 4) o0[j] = r; else o1[j-4] = r;
    }
    *(f32x4*)(out + (size_t)id*8)     = o0;
    *(f32x4*)(out + (size_t)id*8 + 4) = o1;
}

extern "C" void kernel_launch(void* const* d_in, const int* in_sizes, int n_in,
                              void* d_out, int out_size, void* d_ws, size_t ws_size,
                              hipStream_t stream) {
    const int*   x     = (const int*)d_in[0];
    const int*   ke    = (const int*)d_in[1];
    const float* emb   = (const float*)d_in[2];
    const float* W1    = (const float*)d_in[3];
    // d_in[4] = b1: per-column shift cancels exactly through training-mode BN
    const float* g1    = (const float*)d_in[5];
    const float* be1   = (const float*)d_in[6];
    const float* W2    = (const float*)d_in[7];
    // d_in[8] = b2: cancels through final BN (softmax weights sum to 1)
    const float* eps   = (const float*)d_in[9];
    const float* alpha = (const float*)d_in[10];
    const float* bng   = (const float*)d_in[11];
    const float* bnb   = (const float*)d_in[12];

    char* ws = (char*)d_ws;
    unsigned short* hb     = (unsigned short*)(ws + HB_OFF);
    unsigned short* zin    = (unsigned short*)(ws + ZIN_OFF);   // 3 buffers, tiled
    unsigned short* hnb    = (unsigned short*)(ws + HNB_OFF);
    size_t o = O_BASE;
    unsigned short* w1f    = (unsigned short*)(ws + o);          o += 3*65536;
    unsigned short* w2f    = (unsigned short*)(ws + o);          o += 3*65536;
    float*          stats  = (float*)(ws + o);                   o += 32768;  // 3 x 2048 floats
    float*          params = (float*)(ws + o);                   o += 4096;
    int*            rp     = (int*)(ws + o);                     o += 1200128;
    int*            col    = (int*)(ws + o);                     o += 7200000;
    int*            cur    = (int*)(ws + o);                     o += 4096;
    int*            ebase  = (int*)(ws + o);                     o += 4096;
    unsigned int*   pairs  = (unsigned int*)(ws + ZIN_OFF);      // aliased (pre-zin)

    // AtomEncoder (+ zero-pad rows NV..NV+7 for the gather dummy row)
    k_embed<<<12501, 256, 0, stream>>>(x, emb, hb);

    // Weight prep for ALL layers (single dispatch, off the per-layer path)
    k_prep_all<<<dim3(32, LL), 256, 0, stream>>>(W1, W2, alpha, w1f, w2f, params);

    // CSR build (shared by all layers; uses pairs alias before any zin write)
    hipMemsetAsync(cur, 0, KK*NBKT*sizeof(int), stream);
    hipMemsetAsync(stats, 0, 3*2048*sizeof(float), stream);   // all layers' stats
    kA_bin<<<dim3(147, KK), 256, 0, stream>>>(ke, cur, pairs);
    kB_scan<<<1, 256, 0, stream>>>(cur, ebase);
    kB_fill<<<dim3(NBKT, KK), 256, 0, stream>>>(pairs, cur, ebase, rp, col);

    for (int l = 0; l < LL; ++l) {
        float* statsL = stats + (size_t)l*2048;
        unsigned short* w1fl = w1f + (size_t)l*32768;
        unsigned short* w2fl = w2f + (size_t)l*32768;
        k_gather3<<<25000, 256, 0, stream>>>(hb, rp, col, eps + l, zin);
        k_stats3<<<256, 256, 0, stream>>>(zin, w1fl, statsL);
        k_gemm2f<<<256, 512, 0, stream>>>(zin, w1fl, w2fl, g1 + l*D2, be1 + l*D2,
                                          params + l*4, statsL, hnb);
        if (l < LL-1) k_bnapply_mid<<<6250, 256, 0, stream>>>(hnb, statsL,
                                                              bng + l*DD, bnb + l*DD, hb);
        else          k_bnapply_fin<<<6250, 256, 0, stream>>>(hnb, statsL,
                                                              bng + l*DD, bnb + l*DD,
                                                              (float*)d_out);
    }
}